// Round 2
// baseline (4135.510 us; speedup 1.0000x reference)
//
#include <hip/hip_runtime.h>
#include <hip/hip_bf16.h>
#include <math.h>

typedef __bf16 bf16x8 __attribute__((ext_vector_type(8)));
typedef float  f32x4  __attribute__((ext_vector_type(4)));

#define DIM   768
#define HEADS 12
#define DH    64
#define MLP_  3072
#define NTOK  2048
#define SEQ   1024

__device__ __forceinline__ unsigned short f2bf(float f){
  unsigned u = __builtin_bit_cast(unsigned, f);
  u += 0x7fffu + ((u >> 16) & 1u);          // round-to-nearest-even
  return (unsigned short)(u >> 16);
}
__device__ __forceinline__ float bf2f(unsigned short h){
  return __builtin_bit_cast(float, (unsigned)h << 16);
}

__device__ __forceinline__ float wred_sum(float v){
  #pragma unroll
  for (int o = 32; o > 0; o >>= 1) v += __shfl_xor(v, o);
  return v;
}
__device__ __forceinline__ float wred_max(float v){
  #pragma unroll
  for (int o = 32; o > 0; o >>= 1) v = fmaxf(v, __shfl_xor(v, o));
  return v;
}

// ---------------- generic GEMM: C[M,N] = epi(A[M,K] @ B[K,N]) ----------------
// split-bf16 (hi+lo) 3-product MFMA => ~fp32 accuracy. f32 in/out.
// BM=128 BN=64 BK=32, 4 waves (2x2 of 64x32).
#define BM 128
#define BN 64
#define BK 32

__global__ __launch_bounds__(256) void gemm_kernel(
    const float* __restrict__ A, const float* __restrict__ Bw,
    const float* __restrict__ bias, const float* __restrict__ res,
    float* __restrict__ C, int M, int N, int K, int gelu_flag)
{
  __shared__ unsigned short sAh[BM][BK + 8];
  __shared__ unsigned short sAl[BM][BK + 8];
  __shared__ unsigned short sBh[BN][BK + 8];   // [col][k] (transposed)
  __shared__ unsigned short sBl[BN][BK + 8];
  const int tid  = threadIdx.x;
  const int wid  = tid >> 6, lane = tid & 63;
  const int brow = blockIdx.y * BM, bcol = blockIdx.x * BN;
  const int wr   = (wid >> 1) * 64, wc = (wid & 1) * 32;

  f32x4 acc[4][2] = {};

  for (int k0 = 0; k0 < K; k0 += BK){
    // stage A: 128x32 f32 -> bf16 hi+lo
    #pragma unroll
    for (int i = 0; i < 4; i++){
      int idx = tid + i * 256;
      int r = idx >> 3, cv = idx & 7;
      float4 v = *(const float4*)(A + (size_t)(brow + r) * K + k0 + cv * 4);
      ushort4 hv, lv;
      hv.x = f2bf(v.x); lv.x = f2bf(v.x - bf2f(hv.x));
      hv.y = f2bf(v.y); lv.y = f2bf(v.y - bf2f(hv.y));
      hv.z = f2bf(v.z); lv.z = f2bf(v.z - bf2f(hv.z));
      hv.w = f2bf(v.w); lv.w = f2bf(v.w - bf2f(hv.w));
      *(ushort4*)&sAh[r][cv * 4] = hv;
      *(ushort4*)&sAl[r][cv * 4] = lv;
    }
    // stage B: 32x64 f32 -> bf16 hi+lo, transposed into [col][k]
    #pragma unroll
    for (int i = 0; i < 2; i++){
      int idx = tid + i * 256;
      int kr = idx >> 4, cv = idx & 15;
      float4 v = *(const float4*)(Bw + (size_t)(k0 + kr) * N + bcol + cv * 4);
      int c = cv * 4;
      unsigned short h0 = f2bf(v.x), h1 = f2bf(v.y), h2 = f2bf(v.z), h3 = f2bf(v.w);
      sBh[c + 0][kr] = h0; sBl[c + 0][kr] = f2bf(v.x - bf2f(h0));
      sBh[c + 1][kr] = h1; sBl[c + 1][kr] = f2bf(v.y - bf2f(h1));
      sBh[c + 2][kr] = h2; sBl[c + 2][kr] = f2bf(v.z - bf2f(h2));
      sBh[c + 3][kr] = h3; sBl[c + 3][kr] = f2bf(v.w - bf2f(h3));
    }
    __syncthreads();

    bf16x8 ah[4], al[4], bh[2], bl[2];
    #pragma unroll
    for (int m = 0; m < 4; m++){
      int r = wr + m * 16 + (lane & 15), kk = (lane >> 4) * 8;
      ah[m] = *(const bf16x8*)&sAh[r][kk];
      al[m] = *(const bf16x8*)&sAl[r][kk];
    }
    #pragma unroll
    for (int n = 0; n < 2; n++){
      int c = wc + n * 16 + (lane & 15), kk = (lane >> 4) * 8;
      bh[n] = *(const bf16x8*)&sBh[c][kk];
      bl[n] = *(const bf16x8*)&sBl[c][kk];
    }

    #pragma unroll
    for (int m = 0; m < 4; m++)
      #pragma unroll
      for (int n = 0; n < 2; n++){
        acc[m][n] = __builtin_amdgcn_mfma_f32_16x16x32_bf16(al[m], bh[n], acc[m][n], 0, 0, 0);
        acc[m][n] = __builtin_amdgcn_mfma_f32_16x16x32_bf16(ah[m], bl[n], acc[m][n], 0, 0, 0);
        acc[m][n] = __builtin_amdgcn_mfma_f32_16x16x32_bf16(ah[m], bh[n], acc[m][n], 0, 0, 0);
      }
    __syncthreads();
  }

  // epilogue: D layout col=lane&15, row=(lane>>4)*4+reg
  #pragma unroll
  for (int m = 0; m < 4; m++){
    int row0 = brow + wr + m * 16 + ((lane >> 4) << 2);
    #pragma unroll
    for (int n = 0; n < 2; n++){
      int col = bcol + wc + n * 16 + (lane & 15);
      float bv = bias ? bias[col] : 0.f;
      #pragma unroll
      for (int i = 0; i < 4; i++){
        int row = row0 + i;
        float v = acc[m][n][i] + bv;
        if (gelu_flag) v = 0.5f * v * (1.f + erff(v * 0.70710678118654752f));
        if (res) v += res[(size_t)row * N + col];
        C[(size_t)row * N + col] = v;
      }
    }
  }
}

// ---------------- LayerNorm (gamma only, eps 1e-5), one wave per row ----------
__global__ __launch_bounds__(256) void ln_kernel(
    const float* __restrict__ x, const float* __restrict__ g, float* __restrict__ y)
{
  int wid = threadIdx.x >> 6, lane = threadIdx.x & 63;
  int row = blockIdx.x * 4 + wid;
  const float* xr = x + (size_t)row * DIM;
  float v[12]; float s = 0.f;
  #pragma unroll
  for (int d = 0; d < 12; d++){ v[d] = xr[d * 64 + lane]; s += v[d]; }
  s = wred_sum(s);
  float mean = s * (1.f / 768.f);
  float q = 0.f;
  #pragma unroll
  for (int d = 0; d < 12; d++){ float t = v[d] - mean; q += t * t; }
  q = wred_sum(q);
  float rstd = rsqrtf(q * (1.f / 768.f) + 1e-5f);
  float* yr = y + (size_t)row * DIM;
  #pragma unroll
  for (int d = 0; d < 12; d++)
    yr[d * 64 + lane] = (v[d] - mean) * rstd * g[d * 64 + lane];
}

// ---------------- qk rmsnorm: x/||x|| * sqrt(DH) * g, in-place ----------------
__global__ __launch_bounds__(256) void rms_kernel(
    float* __restrict__ buf, const float* __restrict__ g, int ncols)
{
  int wid = threadIdx.x >> 6, lane = threadIdx.x & 63;
  int r = blockIdx.x * 4 + wid;            // [0, 24576)
  int tok = r / HEADS, h = r % HEADS;
  float* p = buf + (size_t)tok * ncols + h * 64;
  float v = p[lane];
  float n2 = wred_sum(v * v);
  float nn = fmaxf(sqrtf(n2), 1e-12f);
  p[lane] = v * (8.f / nn) * g[h * 64 + lane];
}

// ---------------- pos-embed add --------------------------------------------
__global__ __launch_bounds__(256) void posadd_kernel(
    const float* __restrict__ patches, const int* __restrict__ hi,
    const int* __restrict__ wi, const float* __restrict__ ph,
    const float* __restrict__ pw, float* __restrict__ out)
{
  int idx = blockIdx.x * 256 + threadIdx.x;   // over NTOK*192 float4
  int tok = idx / 192, cv = idx % 192;
  float4 p = ((const float4*)patches)[idx];
  float4 a = *(const float4*)(ph + (size_t)hi[tok] * DIM + cv * 4);
  float4 b = *(const float4*)(pw + (size_t)wi[tok] * DIM + cv * 4);
  float4 o;
  o.x = p.x + a.x + b.x; o.y = p.y + a.y + b.y;
  o.z = p.z + a.z + b.z; o.w = p.w + a.w + b.w;
  ((float4*)out)[idx] = o;
}

// ---------------- segment ranges from sorted image_ids -----------------------
__global__ void seg_kernel(const int* __restrict__ ids, int2* __restrict__ segs)
{
  int i = blockIdx.x * 256 + threadIdx.x;   // 0..1023
  int b = blockIdx.y;
  const int* row = ids + b * SEQ;
  int v = row[i];
  int lo = 0, hi = SEQ;
  while (lo < hi){ int mid = (lo + hi) >> 1; if (row[mid] <  v) lo = mid + 1; else hi = mid; }
  int s = lo;
  lo = 0; hi = SEQ;
  while (lo < hi){ int mid = (lo + hi) >> 1; if (row[mid] <= v) lo = mid + 1; else hi = mid; }
  segs[b * SEQ + i] = make_int2(s, lo);
}

// ---------------- segment attention, online softmax, 1 wave / (b,h,q) --------
__global__ __launch_bounds__(256) void attn_kernel(
    const float* __restrict__ qb, const float* __restrict__ kvb,
    const int2* __restrict__ segs, float* __restrict__ ob)
{
  __shared__ float sq[4][64];
  int wid = threadIdx.x >> 6, lane = threadIdx.x & 63;
  int bh = blockIdx.x;
  int b = bh / HEADS, h = bh % HEADS;
  int n = blockIdx.y * 4 + wid;
  size_t tok = (size_t)b * SEQ + n;
  sq[wid][lane] = qb[tok * DIM + h * 64 + lane];
  __syncthreads();
  int2 se = segs[tok];
  const float* kbase = kvb + (size_t)b * SEQ * 1536 + h * 64;
  const float* vbase = kbase + DIM;
  float m = -3.0e38f, l = 0.f, oacc = 0.f;
  for (int j0 = se.x; j0 < se.y; j0 += 64){
    int j = j0 + lane;
    float dot = -3.0e38f;
    if (j < se.y){
      const float4* kp = (const float4*)(kbase + (size_t)j * 1536);
      const float4* q4 = (const float4*)sq[wid];
      float a = 0.f;
      #pragma unroll
      for (int d = 0; d < 16; d++){
        float4 kx = kp[d], qx = q4[d];
        a += kx.x * qx.x; a += kx.y * qx.y; a += kx.z * qx.z; a += kx.w * qx.w;
      }
      dot = a;
    }
    float mnew = fmaxf(m, wred_max(dot));
    float scale = __expf(m - mnew);
    float p = (j < se.y) ? __expf(dot - mnew) : 0.f;
    l = l * scale + wred_sum(p);
    oacc *= scale;
    int jmax = se.y - 1;
    #pragma unroll 8
    for (int jj = 0; jj < 64; jj++){
      float pj = __shfl(p, jj);
      int jg = j0 + jj; jg = jg > jmax ? jmax : jg;   // clamp (pj==0 for invalid)
      oacc += pj * vbase[(size_t)jg * 1536 + lane];
    }
    m = mnew;
  }
  ob[tok * DIM + h * 64 + lane] = oacc / l;
}

// ---------------- driver -----------------------------------------------------
extern "C" void kernel_launch(void* const* d_in, const int* in_sizes, int n_in,
                              void* d_out, int out_size, void* d_ws, size_t ws_size,
                              hipStream_t stream)
{
  const float* patches   = (const float*)d_in[0];
  const int*   h_idx     = (const int*)d_in[1];
  const int*   w_idx     = (const int*)d_in[2];
  const int*   image_ids = (const int*)d_in[3];
  const float* pos_h = (const float*)d_in[4];
  const float* pos_w = (const float*)d_in[5];
  const float* Wp  = (const float*)d_in[6];
  const float* bp  = (const float*)d_in[7];
  const float* lnp = (const float*)d_in[8];
  const float* ln1 = (const float*)d_in[9];
  const float* qg  = (const float*)d_in[10];
  const float* kg  = (const float*)d_in[11];
  const float* Wq  = (const float*)d_in[12];
  const float* Wkv = (const float*)d_in[13];
  const float* Wo  = (const float*)d_in[14];
  const float* ln2 = (const float*)d_in[15];
  const float* W1  = (const float*)d_in[16];
  const float* b1  = (const float*)d_in[17];
  const float* W2  = (const float*)d_in[18];
  const float* b2  = (const float*)d_in[19];
  const float* lnf = (const float*)d_in[20];
  float* out = (float*)d_out;

  float* ws = (float*)d_ws;
  float* x  = ws;                       // 2048*768
  float* xn = x  + NTOK * DIM;          // 2048*768
  float* q  = xn + NTOK * DIM;          // 2048*768   (also embed tmp)
  float* kv = q  + NTOK * DIM;          // 2048*1536
  float* o  = kv + NTOK * 2 * DIM;      // 2048*768
  float* h  = o  + NTOK * DIM;          // 2048*3072  (also pos-added patches)
  int2* segs = (int2*)(h + NTOK * MLP_);

  seg_kernel<<<dim3(4, 2), 256, 0, stream>>>(image_ids, segs);
  posadd_kernel<<<1536, 256, 0, stream>>>(patches, h_idx, w_idx, pos_h, pos_w, h);
  gemm_kernel<<<dim3(DIM / BN, NTOK / BM), 256, 0, stream>>>(
      h, Wp, bp, nullptr, q, NTOK, DIM, DIM, 0);
  ln_kernel<<<NTOK / 4, 256, 0, stream>>>(q, lnp, x);

  for (int i = 0; i < 8; i++){
    ln_kernel<<<NTOK / 4, 256, 0, stream>>>(x, ln1 + i * DIM, xn);
    gemm_kernel<<<dim3(DIM / BN, NTOK / BM), 256, 0, stream>>>(
        xn, Wq + (size_t)i * DIM * DIM, nullptr, nullptr, q, NTOK, DIM, DIM, 0);
    gemm_kernel<<<dim3(2 * DIM / BN, NTOK / BM), 256, 0, stream>>>(
        xn, Wkv + (size_t)i * DIM * 2 * DIM, nullptr, nullptr, kv, NTOK, 2 * DIM, DIM, 0);
    rms_kernel<<<6144, 256, 0, stream>>>(q,  qg + i * HEADS * DH, DIM);
    rms_kernel<<<6144, 256, 0, stream>>>(kv, kg + i * HEADS * DH, 2 * DIM);
    attn_kernel<<<dim3(24, 256), 256, 0, stream>>>(q, kv, segs, o);
    gemm_kernel<<<dim3(DIM / BN, NTOK / BM), 256, 0, stream>>>(
        o, Wo + (size_t)i * DIM * DIM, nullptr, x, x, NTOK, DIM, DIM, 0);
    ln_kernel<<<NTOK / 4, 256, 0, stream>>>(x, ln2 + i * DIM, xn);
    gemm_kernel<<<dim3(MLP_ / BN, NTOK / BM), 256, 0, stream>>>(
        xn, W1 + (size_t)i * DIM * MLP_, b1 + i * MLP_, nullptr, h, NTOK, MLP_, DIM, 1);
    gemm_kernel<<<dim3(DIM / BN, NTOK / BM), 256, 0, stream>>>(
        h, W2 + (size_t)i * MLP_ * DIM, b2 + i * DIM, x, x, NTOK, DIM, MLP_, 0);
  }
  ln_kernel<<<NTOK / 4, 256, 0, stream>>>(x, lnf, out);
}

// Round 3
// 2800.485 us; speedup vs baseline: 1.4767x; 1.4767x over previous
//
#include <hip/hip_runtime.h>
#include <hip/hip_bf16.h>
#include <math.h>

typedef __bf16 bf16x8 __attribute__((ext_vector_type(8)));
typedef float  f32x4  __attribute__((ext_vector_type(4)));
typedef unsigned short ushort_t;

#define DIM   768
#define HEADS 12
#define DH    64
#define MLP_  3072
#define NTOK  2048
#define SEQ   1024
#define WELTS 7077888   // per-layer converted weight elements (Wq+Wkv+Wo+W1+W2)

__device__ __forceinline__ ushort_t f2bf(float f){
  unsigned u = __builtin_bit_cast(unsigned, f);
  u += 0x7fffu + ((u >> 16) & 1u);          // round-to-nearest-even
  return (ushort_t)(u >> 16);
}
__device__ __forceinline__ float bf2f(ushort_t h){
  return __builtin_bit_cast(float, (unsigned)h << 16);
}
__device__ __forceinline__ void gload16(const void* g, void* l){
  __builtin_amdgcn_global_load_lds(
      (const __attribute__((address_space(1))) void*)g,
      (__attribute__((address_space(3))) void*)l, 16, 0, 0);
}
__device__ __forceinline__ float wred_sum(float v){
  #pragma unroll
  for (int o = 32; o > 0; o >>= 1) v += __shfl_xor(v, o);
  return v;
}
__device__ __forceinline__ float wred_max(float v){
  #pragma unroll
  for (int o = 32; o > 0; o >>= 1) v = fmaxf(v, __shfl_xor(v, o));
  return v;
}

// ---------- weight convert: W[K][N] f32 -> Wt_h/Wt_l [N][K] bf16 -------------
// tile 32(k) x 64(n) per block, 256 threads.
__global__ __launch_bounds__(256) void convert_w_kernel(
    const float* __restrict__ Wq, const float* __restrict__ Wkv,
    const float* __restrict__ Wo, const float* __restrict__ W1,
    const float* __restrict__ W2, int layer, int wp_only,
    ushort_t* __restrict__ th, ushort_t* __restrict__ tl)
{
  int bid = blockIdx.x;
  const float* src; int K, N; size_t ooff; int t;
  if (wp_only){ src = Wq; K = 768; N = 768; ooff = 0; t = bid; }
  else if (bid < 288) { src = Wq;  K = 768;  N = 768;  ooff = 0;       t = bid; }
  else if (bid < 864) { src = Wkv; K = 768;  N = 1536; ooff = 589824;  t = bid - 288; }
  else if (bid < 1152){ src = Wo;  K = 768;  N = 768;  ooff = 1769472; t = bid - 864; }
  else if (bid < 2304){ src = W1;  K = 768;  N = 3072; ooff = 2359296; t = bid - 1152; }
  else                { src = W2;  K = 3072; N = 768;  ooff = 4718592; t = bid - 2304; }
  if (!wp_only) src += (size_t)layer * K * N;
  int ntn = N >> 6;
  int tk = t / ntn, tn = t % ntn;
  int k0 = tk * 32, n0 = tn * 64;

  __shared__ ushort_t lh[32][66];   // [k][n], +2 pad
  __shared__ ushort_t ll[32][66];
  int tid = threadIdx.x;
  #pragma unroll
  for (int rr = 0; rr < 2; rr++){
    int k = rr * 16 + (tid >> 4);
    int n = (tid & 15) * 4;
    float4 v = *(const float4*)(src + (size_t)(k0 + k) * N + n0 + n);
    ushort_t h0 = f2bf(v.x), h1 = f2bf(v.y), h2 = f2bf(v.z), h3 = f2bf(v.w);
    lh[k][n+0] = h0; ll[k][n+0] = f2bf(v.x - bf2f(h0));
    lh[k][n+1] = h1; ll[k][n+1] = f2bf(v.y - bf2f(h1));
    lh[k][n+2] = h2; ll[k][n+2] = f2bf(v.z - bf2f(h2));
    lh[k][n+3] = h3; ll[k][n+3] = f2bf(v.w - bf2f(h3));
  }
  __syncthreads();
  // write out: n = tid>>2, kq = tid&3 -> 16B chunk, 4 lanes cover 64B of a row
  int n = tid >> 2, kq = tid & 3;
  unsigned ph[4], pl[4];
  #pragma unroll
  for (int j = 0; j < 4; j++){
    ph[j] = (unsigned)lh[kq*8 + 2*j][n] | ((unsigned)lh[kq*8 + 2*j + 1][n] << 16);
    pl[j] = (unsigned)ll[kq*8 + 2*j][n] | ((unsigned)ll[kq*8 + 2*j + 1][n] << 16);
  }
  size_t obase = ooff + (size_t)(n0 + n) * K + k0 + kq * 8;
  *(uint4*)(th + obase) = make_uint4(ph[0], ph[1], ph[2], ph[3]);
  *(uint4*)(tl + obase) = make_uint4(pl[0], pl[1], pl[2], pl[3]);
}

// ---------------- GEMM: C[M,N] = epi(A[M,K] @ Wt[N,K]^T) ---------------------
// A, Wt pre-split bf16 hi/lo, both k-major. BM=64 BN=64 BK=32, 8 waves:
// 2x2 of 32x32 quadrants x 2 k-halves (in-block split-K, LDS reduce).
// mode 0: f32 out (+bias)(+res);  mode 1: bf16 hi/lo out of gelu(acc+bias).
__global__ __launch_bounds__(512) void gemm_kernel(
    const ushort_t* __restrict__ Ah, const ushort_t* __restrict__ Al,
    const ushort_t* __restrict__ Bh, const ushort_t* __restrict__ Bl,
    const float* __restrict__ bias, const float* __restrict__ res,
    float* __restrict__ C, ushort_t* __restrict__ Ch, ushort_t* __restrict__ Cl,
    int M, int N, int K, int mode)
{
  __shared__ ushort_t sA[2][2][64][32];   // [kgroup][h/l][row][k]  16 KB
  __shared__ ushort_t sB[2][2][64][32];   // [kgroup][h/l][col][k]  16 KB
  const int tid = threadIdx.x;
  const int wid = tid >> 6, lane = tid & 63;
  const int g = wid >> 2, m2 = wid & 1, n2 = (wid >> 1) & 1, lw = wid & 3;
  const int brow = blockIdx.y * 64, bcol = blockIdx.x * 64;
  const int khalf = K >> 1, nk = khalf >> 5;

  const ushort_t* pAh = Ah + (size_t)brow * K + (size_t)g * khalf;
  const ushort_t* pAl = Al + (size_t)brow * K + (size_t)g * khalf;
  const ushort_t* pBh = Bh + (size_t)bcol * K + (size_t)g * khalf;
  const ushort_t* pBl = Bl + (size_t)bcol * K + (size_t)g * khalf;

  const int sr = lw * 16 + (lane >> 2);       // staged row/col (0..63)
  const int sk = (lane & 3) * 8;              // staged k-octet
  const size_t soff = (size_t)sr * K + sk;

  ushort_t* dAh = &sA[g][0][lw * 16][0];
  ushort_t* dAl = &sA[g][1][lw * 16][0];
  ushort_t* dBh = &sB[g][0][lw * 16][0];
  ushort_t* dBl = &sB[g][1][lw * 16][0];

  const int fr = lane & 15, fk = (lane >> 4) * 8;
  f32x4 acc[2][2] = {};

  for (int ks = 0; ks < nk; ks++){
    int k0 = ks * 32;
    gload16(pAh + soff + k0, dAh);
    gload16(pAl + soff + k0, dAl);
    gload16(pBh + soff + k0, dBh);
    gload16(pBl + soff + k0, dBl);
    __syncthreads();

    bf16x8 ah[2], al[2], bh[2], bl[2];
    #pragma unroll
    for (int m = 0; m < 2; m++){
      ah[m] = *(const bf16x8*)&sA[g][0][m2 * 32 + m * 16 + fr][fk];
      al[m] = *(const bf16x8*)&sA[g][1][m2 * 32 + m * 16 + fr][fk];
    }
    #pragma unroll
    for (int n = 0; n < 2; n++){
      bh[n] = *(const bf16x8*)&sB[g][0][n2 * 32 + n * 16 + fr][fk];
      bl[n] = *(const bf16x8*)&sB[g][1][n2 * 32 + n * 16 + fr][fk];
    }
    #pragma unroll
    for (int m = 0; m < 2; m++)
      #pragma unroll
      for (int n = 0; n < 2; n++){
        acc[m][n] = __builtin_amdgcn_mfma_f32_16x16x32_bf16(al[m], bh[n], acc[m][n], 0, 0, 0);
        acc[m][n] = __builtin_amdgcn_mfma_f32_16x16x32_bf16(ah[m], bl[n], acc[m][n], 0, 0, 0);
        acc[m][n] = __builtin_amdgcn_mfma_f32_16x16x32_bf16(ah[m], bh[n], acc[m][n], 0, 0, 0);
      }
    __syncthreads();
  }

  // in-block split-K reduction (reuse sA as 16 KB f32 scratch)
  float* red = (float*)sA;
  if (g == 1){
    float* p = red + ((size_t)lw * 64 + lane) * 16;
    #pragma unroll
    for (int m = 0; m < 2; m++)
      #pragma unroll
      for (int n = 0; n < 2; n++)
        *(f32x4*)(p + (m * 2 + n) * 4) = acc[m][n];
  }
  __syncthreads();
  if (g == 0){
    const float* p = red + ((size_t)lw * 64 + lane) * 16;
    #pragma unroll
    for (int m = 0; m < 2; m++)
      #pragma unroll
      for (int n = 0; n < 2; n++)
        acc[m][n] += *(const f32x4*)(p + (m * 2 + n) * 4);

    #pragma unroll
    for (int n = 0; n < 2; n++){
      int col = bcol + n2 * 32 + n * 16 + fr;
      float bv = bias ? bias[col] : 0.f;
      #pragma unroll
      for (int m = 0; m < 2; m++){
        int row0 = brow + m2 * 32 + m * 16 + ((lane >> 4) << 2);
        #pragma unroll
        for (int i = 0; i < 4; i++){
          int row = row0 + i;
          float v = acc[m][n][i] + bv;
          size_t o = (size_t)row * N + col;
          if (mode == 1){
            float ge = 0.5f * v * (1.f + erff(v * 0.70710678118654752f));
            ushort_t hi = f2bf(ge);
            Ch[o] = hi; Cl[o] = f2bf(ge - bf2f(hi));
          } else {
            if (res) v += res[o];
            C[o] = v;
          }
        }
      }
    }
  }
}

// ---------------- LayerNorm; out = f32 (yf) or bf16 hi/lo pair ---------------
__global__ __launch_bounds__(256) void ln_kernel(
    const float* __restrict__ x, const float* __restrict__ g,
    float* __restrict__ yf, ushort_t* __restrict__ yh, ushort_t* __restrict__ yl)
{
  int wid = threadIdx.x >> 6, lane = threadIdx.x & 63;
  int row = blockIdx.x * 4 + wid;
  const float* xr = x + (size_t)row * DIM;
  float v[12]; float s = 0.f;
  #pragma unroll
  for (int d = 0; d < 12; d++){ v[d] = xr[d * 64 + lane]; s += v[d]; }
  s = wred_sum(s);
  float mean = s * (1.f / 768.f);
  float q = 0.f;
  #pragma unroll
  for (int d = 0; d < 12; d++){ float t = v[d] - mean; q += t * t; }
  q = wred_sum(q);
  float rstd = rsqrtf(q * (1.f / 768.f) + 1e-5f);
  size_t base = (size_t)row * DIM;
  #pragma unroll
  for (int d = 0; d < 12; d++){
    float y = (v[d] - mean) * rstd * g[d * 64 + lane];
    if (yf) yf[base + d * 64 + lane] = y;
    else {
      ushort_t hi = f2bf(y);
      yh[base + d * 64 + lane] = hi;
      yl[base + d * 64 + lane] = f2bf(y - bf2f(hi));
    }
  }
}

// ------------- fused qk rmsnorm for q and kv(k-part), in-place ---------------
__global__ __launch_bounds__(256) void rms_kernel(
    float* __restrict__ q, float* __restrict__ kv,
    const float* __restrict__ qg, const float* __restrict__ kg)
{
  int wid = threadIdx.x >> 6, lane = threadIdx.x & 63;
  int id = blockIdx.x * 4 + wid;            // [0, 49152)
  float* p; const float* g;
  if (id < 24576){
    int tok = id / HEADS, h = id % HEADS;
    p = q + (size_t)tok * DIM + h * 64; g = qg + h * 64;
  } else {
    int id2 = id - 24576;
    int tok = id2 / HEADS, h = id2 % HEADS;
    p = kv + (size_t)tok * 1536 + h * 64; g = kg + h * 64;
  }
  float v = p[lane];
  float n2 = wred_sum(v * v);
  float nn = fmaxf(sqrtf(n2), 1e-12f);
  p[lane] = v * (8.f / nn) * g[lane];
}

// ---------------- pos-embed add -> bf16 hi/lo pair ---------------------------
__global__ __launch_bounds__(256) void posadd_kernel(
    const float* __restrict__ patches, const int* __restrict__ hi,
    const int* __restrict__ wi, const float* __restrict__ ph,
    const float* __restrict__ pw, ushort_t* __restrict__ oh, ushort_t* __restrict__ ol)
{
  int idx = blockIdx.x * 256 + threadIdx.x;   // over NTOK*192 float4
  int tok = idx / 192, cv = idx % 192;
  float4 p = ((const float4*)patches)[idx];
  float4 a = *(const float4*)(ph + (size_t)hi[tok] * DIM + cv * 4);
  float4 b = *(const float4*)(pw + (size_t)wi[tok] * DIM + cv * 4);
  float o0 = p.x + a.x + b.x, o1 = p.y + a.y + b.y;
  float o2 = p.z + a.z + b.z, o3 = p.w + a.w + b.w;
  ushort_t h0 = f2bf(o0), h1 = f2bf(o1), h2 = f2bf(o2), h3 = f2bf(o3);
  ushort4 hv = make_ushort4(h0, h1, h2, h3);
  ushort4 lv = make_ushort4(f2bf(o0 - bf2f(h0)), f2bf(o1 - bf2f(h1)),
                            f2bf(o2 - bf2f(h2)), f2bf(o3 - bf2f(h3)));
  ((ushort4*)oh)[idx] = hv;
  ((ushort4*)ol)[idx] = lv;
}

// ---------------- segment ranges from sorted image_ids -----------------------
__global__ void seg_kernel(const int* __restrict__ ids, int2* __restrict__ segs)
{
  int i = blockIdx.x * 256 + threadIdx.x;   // 0..1023
  int b = blockIdx.y;
  const int* row = ids + b * SEQ;
  int v = row[i];
  int lo = 0, hi = SEQ;
  while (lo < hi){ int mid = (lo + hi) >> 1; if (row[mid] <  v) lo = mid + 1; else hi = mid; }
  int s = lo;
  lo = 0; hi = SEQ;
  while (lo < hi){ int mid = (lo + hi) >> 1; if (row[mid] <= v) lo = mid + 1; else hi = mid; }
  segs[b * SEQ + i] = make_int2(s, lo);
}

// ---------------- segment attention, online softmax, 1 wave / (b,h,q) --------
__global__ __launch_bounds__(256) void attn_kernel(
    const float* __restrict__ qb, const float* __restrict__ kvb,
    const int2* __restrict__ segs, ushort_t* __restrict__ oh, ushort_t* __restrict__ ol)
{
  __shared__ float sq[4][64];
  int wid = threadIdx.x >> 6, lane = threadIdx.x & 63;
  int bh = blockIdx.x;
  int b = bh / HEADS, h = bh % HEADS;
  int n = blockIdx.y * 4 + wid;
  size_t tok = (size_t)b * SEQ + n;
  sq[wid][lane] = qb[tok * DIM + h * 64 + lane];
  __syncthreads();
  int2 se = segs[tok];
  const float* kbase = kvb + (size_t)b * SEQ * 1536 + h * 64;
  const float* vbase = kbase + DIM;
  float m = -3.0e38f, l = 0.f, oacc = 0.f;
  for (int j0 = se.x; j0 < se.y; j0 += 64){
    int j = j0 + lane;
    float dot = -3.0e38f;
    if (j < se.y){
      const float4* kp = (const float4*)(kbase + (size_t)j * 1536);
      const float4* q4 = (const float4*)sq[wid];
      float a = 0.f;
      #pragma unroll
      for (int d = 0; d < 16; d++){
        float4 kx = kp[d], qx = q4[d];
        a += kx.x * qx.x; a += kx.y * qx.y; a += kx.z * qx.z; a += kx.w * qx.w;
      }
      dot = a;
    }
    float mnew = fmaxf(m, wred_max(dot));
    float scale = __expf(m - mnew);
    float p = (j < se.y) ? __expf(dot - mnew) : 0.f;
    l = l * scale + wred_sum(p);
    oacc *= scale;
    int jmax = se.y - 1;
    #pragma unroll 8
    for (int jj = 0; jj < 64; jj++){
      float pj = __shfl(p, jj);
      int jg = j0 + jj; jg = jg > jmax ? jmax : jg;
      oacc += pj * vbase[(size_t)jg * 1536 + lane];
    }
    m = mnew;
  }
  float v = oacc / l;
  ushort_t hi2 = f2bf(v);
  size_t o = tok * DIM + h * 64 + lane;
  oh[o] = hi2; ol[o] = f2bf(v - bf2f(hi2));
}

// ---------------- driver -----------------------------------------------------
extern "C" void kernel_launch(void* const* d_in, const int* in_sizes, int n_in,
                              void* d_out, int out_size, void* d_ws, size_t ws_size,
                              hipStream_t stream)
{
  const float* patches   = (const float*)d_in[0];
  const int*   h_idx     = (const int*)d_in[1];
  const int*   w_idx     = (const int*)d_in[2];
  const int*   image_ids = (const int*)d_in[3];
  const float* pos_h = (const float*)d_in[4];
  const float* pos_w = (const float*)d_in[5];
  const float* Wp  = (const float*)d_in[6];
  const float* bp  = (const float*)d_in[7];
  const float* lnp = (const float*)d_in[8];
  const float* ln1 = (const float*)d_in[9];
  const float* qg  = (const float*)d_in[10];
  const float* kg  = (const float*)d_in[11];
  const float* Wq  = (const float*)d_in[12];
  const float* Wkv = (const float*)d_in[13];
  const float* Wo  = (const float*)d_in[14];
  const float* ln2 = (const float*)d_in[15];
  const float* W1  = (const float*)d_in[16];
  const float* b1  = (const float*)d_in[17];
  const float* W2  = (const float*)d_in[18];
  const float* b2  = (const float*)d_in[19];
  const float* lnf = (const float*)d_in[20];
  float* out = (float*)d_out;

  float* ws = (float*)d_ws;
  float* x  = ws;                        // 2048*768 f32
  float* q  = x  + NTOK * DIM;           // 2048*768 f32
  float* kv = q  + NTOK * DIM;           // 2048*1536 f32
  ushort_t* aAh = (ushort_t*)(kv + NTOK * 2 * DIM);   // 2048*768 bf16 pair
  ushort_t* aAl = aAh + NTOK * DIM;
  ushort_t* aBh = aAl + NTOK * DIM;                    // 2048*3072 bf16 pair
  ushort_t* aBl = aBh + NTOK * MLP_;
  ushort_t* wth = aBl + NTOK * MLP_;                   // per-layer weights
  ushort_t* wtl = wth + WELTS;
  int2* segs = (int2*)(wtl + WELTS);

  seg_kernel<<<dim3(4, 2), 256, 0, stream>>>(image_ids, segs);
  posadd_kernel<<<1536, 256, 0, stream>>>(patches, h_idx, w_idx, pos_h, pos_w, aAh, aAl);
  convert_w_kernel<<<288, 256, 0, stream>>>(Wp, nullptr, nullptr, nullptr, nullptr, 0, 1, wth, wtl);
  gemm_kernel<<<dim3(12, 32), 512, 0, stream>>>(
      aAh, aAl, wth, wtl, bp, nullptr, q, nullptr, nullptr, NTOK, DIM, DIM, 0);
  ln_kernel<<<NTOK / 4, 256, 0, stream>>>(q, lnp, x, nullptr, nullptr);

  for (int i = 0; i < 8; i++){
    convert_w_kernel<<<3456, 256, 0, stream>>>(
        Wq, Wkv, Wo, W1, W2, i, 0, wth, wtl);
    ln_kernel<<<NTOK / 4, 256, 0, stream>>>(x, ln1 + i * DIM, nullptr, aAh, aAl);
    gemm_kernel<<<dim3(12, 32), 512, 0, stream>>>(
        aAh, aAl, wth + 0, wtl + 0, nullptr, nullptr, q, nullptr, nullptr,
        NTOK, DIM, DIM, 0);
    gemm_kernel<<<dim3(24, 32), 512, 0, stream>>>(
        aAh, aAl, wth + 589824, wtl + 589824, nullptr, nullptr, kv, nullptr, nullptr,
        NTOK, 2 * DIM, DIM, 0);
    rms_kernel<<<12288, 256, 0, stream>>>(q, kv, qg + i * HEADS * DH, kg + i * HEADS * DH);
    attn_kernel<<<dim3(24, 256), 256, 0, stream>>>(q, kv, segs, aAh, aAl);
    gemm_kernel<<<dim3(12, 32), 512, 0, stream>>>(
        aAh, aAl, wth + 1769472, wtl + 1769472, nullptr, x, x, nullptr, nullptr,
        NTOK, DIM, DIM, 0);
    ln_kernel<<<NTOK / 4, 256, 0, stream>>>(x, ln2 + i * DIM, nullptr, aAh, aAl);
    gemm_kernel<<<dim3(48, 32), 512, 0, stream>>>(
        aAh, aAl, wth + 2359296, wtl + 2359296, b1 + i * MLP_, nullptr,
        nullptr, aBh, aBl, NTOK, MLP_, DIM, 1);
    gemm_kernel<<<dim3(12, 32), 512, 0, stream>>>(
        aBh, aBl, wth + 4718592, wtl + 4718592, b2 + i * DIM, x, x, nullptr, nullptr,
        NTOK, DIM, MLP_, 0);
  }
  ln_kernel<<<NTOK / 4, 256, 0, stream>>>(x, lnf, out, nullptr, nullptr);
}

// Round 4
// 1918.876 us; speedup vs baseline: 2.1552x; 1.4594x over previous
//
#include <hip/hip_runtime.h>
#include <hip/hip_bf16.h>
#include <math.h>

typedef __bf16 bf16x8 __attribute__((ext_vector_type(8)));
typedef float  f32x4  __attribute__((ext_vector_type(4)));
typedef unsigned short ushort_t;

#define DIM   768
#define HEADS 12
#define DH    64
#define MLP_  3072
#define NTOK  2048
#define SEQ   1024
#define WELTS 7077888   // per-layer converted weight elements (Wq+Wkv+Wo+W1+W2)

__device__ __forceinline__ ushort_t f2bf(float f){
  unsigned u = __builtin_bit_cast(unsigned, f);
  u += 0x7fffu + ((u >> 16) & 1u);          // round-to-nearest-even
  return (ushort_t)(u >> 16);
}
__device__ __forceinline__ float bf2f(ushort_t h){
  return __builtin_bit_cast(float, (unsigned)h << 16);
}
__device__ __forceinline__ unsigned pk2(float a, float b){
  return (unsigned)f2bf(a) | ((unsigned)f2bf(b) << 16);
}
__device__ __forceinline__ void gload16(const void* g, void* l){
  __builtin_amdgcn_global_load_lds(
      (const __attribute__((address_space(1))) void*)g,
      (__attribute__((address_space(3))) void*)l, 16, 0, 0);
}
__device__ __forceinline__ float wred_sum(float v){
  #pragma unroll
  for (int o = 32; o > 0; o >>= 1) v += __shfl_xor(v, o);
  return v;
}

// ---------- weight convert: W[K][N] f32 -> Wt_h/Wt_l [N][K] bf16 -------------
__global__ __launch_bounds__(256) void convert_w_kernel(
    const float* __restrict__ Wq, const float* __restrict__ Wkv,
    const float* __restrict__ Wo, const float* __restrict__ W1,
    const float* __restrict__ W2, int layer, int wp_only,
    ushort_t* __restrict__ th, ushort_t* __restrict__ tl)
{
  int bid = blockIdx.x;
  const float* src; int K, N; size_t ooff; int t;
  if (wp_only){ src = Wq; K = 768; N = 768; ooff = 0; t = bid; }
  else if (bid < 288) { src = Wq;  K = 768;  N = 768;  ooff = 0;       t = bid; }
  else if (bid < 864) { src = Wkv; K = 768;  N = 1536; ooff = 589824;  t = bid - 288; }
  else if (bid < 1152){ src = Wo;  K = 768;  N = 768;  ooff = 1769472; t = bid - 864; }
  else if (bid < 2304){ src = W1;  K = 768;  N = 3072; ooff = 2359296; t = bid - 1152; }
  else                { src = W2;  K = 3072; N = 768;  ooff = 4718592; t = bid - 2304; }
  if (!wp_only) src += (size_t)layer * K * N;
  int ntn = N >> 6;
  int tk = t / ntn, tn = t % ntn;
  int k0 = tk * 32, n0 = tn * 64;

  __shared__ ushort_t lh[32][66];
  __shared__ ushort_t ll[32][66];
  int tid = threadIdx.x;
  #pragma unroll
  for (int rr = 0; rr < 2; rr++){
    int k = rr * 16 + (tid >> 4);
    int n = (tid & 15) * 4;
    float4 v = *(const float4*)(src + (size_t)(k0 + k) * N + n0 + n);
    ushort_t h0 = f2bf(v.x), h1 = f2bf(v.y), h2 = f2bf(v.z), h3 = f2bf(v.w);
    lh[k][n+0] = h0; ll[k][n+0] = f2bf(v.x - bf2f(h0));
    lh[k][n+1] = h1; ll[k][n+1] = f2bf(v.y - bf2f(h1));
    lh[k][n+2] = h2; ll[k][n+2] = f2bf(v.z - bf2f(h2));
    lh[k][n+3] = h3; ll[k][n+3] = f2bf(v.w - bf2f(h3));
  }
  __syncthreads();
  int n = tid >> 2, kq = tid & 3;
  unsigned ph[4], pl[4];
  #pragma unroll
  for (int j = 0; j < 4; j++){
    ph[j] = (unsigned)lh[kq*8 + 2*j][n] | ((unsigned)lh[kq*8 + 2*j + 1][n] << 16);
    pl[j] = (unsigned)ll[kq*8 + 2*j][n] | ((unsigned)ll[kq*8 + 2*j + 1][n] << 16);
  }
  size_t obase = ooff + (size_t)(n0 + n) * K + k0 + kq * 8;
  *(uint4*)(th + obase) = make_uint4(ph[0], ph[1], ph[2], ph[3]);
  *(uint4*)(tl + obase) = make_uint4(pl[0], pl[1], pl[2], pl[3]);
}

// ---------------- GEMM: C[M,N] = epi(A[M,K] @ Wt[N,K]^T) ---------------------
// mode 0: f32 out (+bias)(+res); mode 1: bf16 hi/lo out of gelu(acc+bias);
// mode 2 (kv): col<768 -> f32 k-buffer (stride 768); col>=768 -> Vt bf16 transposed.
__global__ __launch_bounds__(512) void gemm_kernel(
    const ushort_t* __restrict__ Ah, const ushort_t* __restrict__ Al,
    const ushort_t* __restrict__ Bh, const ushort_t* __restrict__ Bl,
    const float* __restrict__ bias, const float* __restrict__ res,
    float* __restrict__ C, ushort_t* __restrict__ Ch, ushort_t* __restrict__ Cl,
    ushort_t* __restrict__ Vt, int M, int N, int K, int mode)
{
  __shared__ ushort_t sA[2][2][64][32];
  __shared__ ushort_t sB[2][2][64][32];
  const int tid = threadIdx.x;
  const int wid = tid >> 6, lane = tid & 63;
  const int g = wid >> 2, m2 = wid & 1, n2 = (wid >> 1) & 1, lw = wid & 3;
  const int brow = blockIdx.y * 64, bcol = blockIdx.x * 64;
  const int khalf = K >> 1, nk = khalf >> 5;

  const ushort_t* pAh = Ah + (size_t)brow * K + (size_t)g * khalf;
  const ushort_t* pAl = Al + (size_t)brow * K + (size_t)g * khalf;
  const ushort_t* pBh = Bh + (size_t)bcol * K + (size_t)g * khalf;
  const ushort_t* pBl = Bl + (size_t)bcol * K + (size_t)g * khalf;

  const int sr = lw * 16 + (lane >> 2);
  const int sk = (lane & 3) * 8;
  const size_t soff = (size_t)sr * K + sk;

  ushort_t* dAh = &sA[g][0][lw * 16][0];
  ushort_t* dAl = &sA[g][1][lw * 16][0];
  ushort_t* dBh = &sB[g][0][lw * 16][0];
  ushort_t* dBl = &sB[g][1][lw * 16][0];

  const int fr = lane & 15, fk = (lane >> 4) * 8;
  f32x4 acc[2][2] = {};

  for (int ks = 0; ks < nk; ks++){
    int k0 = ks * 32;
    gload16(pAh + soff + k0, dAh);
    gload16(pAl + soff + k0, dAl);
    gload16(pBh + soff + k0, dBh);
    gload16(pBl + soff + k0, dBl);
    __syncthreads();

    bf16x8 ah[2], al[2], bh[2], bl[2];
    #pragma unroll
    for (int m = 0; m < 2; m++){
      ah[m] = *(const bf16x8*)&sA[g][0][m2 * 32 + m * 16 + fr][fk];
      al[m] = *(const bf16x8*)&sA[g][1][m2 * 32 + m * 16 + fr][fk];
    }
    #pragma unroll
    for (int n = 0; n < 2; n++){
      bh[n] = *(const bf16x8*)&sB[g][0][n2 * 32 + n * 16 + fr][fk];
      bl[n] = *(const bf16x8*)&sB[g][1][n2 * 32 + n * 16 + fr][fk];
    }
    #pragma unroll
    for (int m = 0; m < 2; m++)
      #pragma unroll
      for (int n = 0; n < 2; n++){
        acc[m][n] = __builtin_amdgcn_mfma_f32_16x16x32_bf16(al[m], bh[n], acc[m][n], 0, 0, 0);
        acc[m][n] = __builtin_amdgcn_mfma_f32_16x16x32_bf16(ah[m], bl[n], acc[m][n], 0, 0, 0);
        acc[m][n] = __builtin_amdgcn_mfma_f32_16x16x32_bf16(ah[m], bh[n], acc[m][n], 0, 0, 0);
      }
    __syncthreads();
  }

  float* red = (float*)sA;
  if (g == 1){
    float* p = red + ((size_t)lw * 64 + lane) * 16;
    #pragma unroll
    for (int m = 0; m < 2; m++)
      #pragma unroll
      for (int n = 0; n < 2; n++)
        *(f32x4*)(p + (m * 2 + n) * 4) = acc[m][n];
  }
  __syncthreads();
  if (g == 0){
    const float* p = red + ((size_t)lw * 64 + lane) * 16;
    #pragma unroll
    for (int m = 0; m < 2; m++)
      #pragma unroll
      for (int n = 0; n < 2; n++)
        acc[m][n] += *(const f32x4*)(p + (m * 2 + n) * 4);

    #pragma unroll
    for (int n = 0; n < 2; n++){
      int col = bcol + n2 * 32 + n * 16 + fr;
      float bv = bias ? bias[col] : 0.f;
      #pragma unroll
      for (int m = 0; m < 2; m++){
        int row0 = brow + m2 * 32 + m * 16 + ((lane >> 4) << 2);
        if (mode == 2){
          if (col < 768){
            #pragma unroll
            for (int i = 0; i < 4; i++)
              C[(size_t)(row0 + i) * 768 + col] = acc[m][n][i];
          } else {
            int hcol = col - 768, hh = hcol >> 6, dd = hcol & 63;
            int bq = row0 >> 10, tok0 = row0 & 1023;
            ushort4 sv;
            sv.x = f2bf(acc[m][n][0]); sv.y = f2bf(acc[m][n][1]);
            sv.z = f2bf(acc[m][n][2]); sv.w = f2bf(acc[m][n][3]);
            *(ushort4*)(Vt + ((size_t)((bq * 12 + hh) * 64 + dd)) * 1024 + tok0) = sv;
          }
        } else {
          #pragma unroll
          for (int i = 0; i < 4; i++){
            int row = row0 + i;
            float v = acc[m][n][i] + bv;
            size_t o = (size_t)row * N + col;
            if (mode == 1){
              float ge = 0.5f * v * (1.f + erff(v * 0.70710678118654752f));
              ushort_t hi = f2bf(ge);
              Ch[o] = hi; Cl[o] = f2bf(ge - bf2f(hi));
            } else {
              if (res) v += res[o];
              C[o] = v;
            }
          }
        }
      }
    }
  }
}

// ---------------- LayerNorm; out = f32 (yf) or bf16 hi/lo pair ---------------
__global__ __launch_bounds__(256) void ln_kernel(
    const float* __restrict__ x, const float* __restrict__ g,
    float* __restrict__ yf, ushort_t* __restrict__ yh, ushort_t* __restrict__ yl)
{
  int wid = threadIdx.x >> 6, lane = threadIdx.x & 63;
  int row = blockIdx.x * 4 + wid;
  const float* xr = x + (size_t)row * DIM;
  float v[12]; float s = 0.f;
  #pragma unroll
  for (int d = 0; d < 12; d++){ v[d] = xr[d * 64 + lane]; s += v[d]; }
  s = wred_sum(s);
  float mean = s * (1.f / 768.f);
  float q = 0.f;
  #pragma unroll
  for (int d = 0; d < 12; d++){ float t = v[d] - mean; q += t * t; }
  q = wred_sum(q);
  float rstd = rsqrtf(q * (1.f / 768.f) + 1e-5f);
  size_t base = (size_t)row * DIM;
  #pragma unroll
  for (int d = 0; d < 12; d++){
    float y = (v[d] - mean) * rstd * g[d * 64 + lane];
    if (yf) yf[base + d * 64 + lane] = y;
    else {
      ushort_t hi = f2bf(y);
      yh[base + d * 64 + lane] = hi;
      yl[base + d * 64 + lane] = f2bf(y - bf2f(hi));
    }
  }
}

// ------------- fused qk rmsnorm for q and k buffers, in-place ----------------
__global__ __launch_bounds__(256) void rms_kernel(
    float* __restrict__ q, float* __restrict__ kb,
    const float* __restrict__ qg, const float* __restrict__ kg)
{
  int wid = threadIdx.x >> 6, lane = threadIdx.x & 63;
  int id = blockIdx.x * 4 + wid;            // [0, 49152)
  float* p; const float* g;
  int id2 = id < 24576 ? id : id - 24576;
  int tok = id2 / HEADS, h = id2 % HEADS;
  if (id < 24576){ p = q  + (size_t)tok * DIM + h * 64; g = qg + h * 64; }
  else           { p = kb + (size_t)tok * DIM + h * 64; g = kg + h * 64; }
  float v = p[lane];
  float n2 = wred_sum(v * v);
  float nn = fmaxf(sqrtf(n2), 1e-12f);
  p[lane] = v * (8.f / nn) * g[lane];
}

// ---------------- pos-embed add -> bf16 hi/lo pair ---------------------------
__global__ __launch_bounds__(256) void posadd_kernel(
    const float* __restrict__ patches, const int* __restrict__ hi,
    const int* __restrict__ wi, const float* __restrict__ ph,
    const float* __restrict__ pw, ushort_t* __restrict__ oh, ushort_t* __restrict__ ol)
{
  int idx = blockIdx.x * 256 + threadIdx.x;
  int tok = idx / 192, cv = idx % 192;
  float4 p = ((const float4*)patches)[idx];
  float4 a = *(const float4*)(ph + (size_t)hi[tok] * DIM + cv * 4);
  float4 b = *(const float4*)(pw + (size_t)wi[tok] * DIM + cv * 4);
  float o0 = p.x + a.x + b.x, o1 = p.y + a.y + b.y;
  float o2 = p.z + a.z + b.z, o3 = p.w + a.w + b.w;
  ushort_t h0 = f2bf(o0), h1 = f2bf(o1), h2 = f2bf(o2), h3 = f2bf(o3);
  ((ushort4*)oh)[idx] = make_ushort4(h0, h1, h2, h3);
  ((ushort4*)ol)[idx] = make_ushort4(f2bf(o0 - bf2f(h0)), f2bf(o1 - bf2f(h1)),
                                     f2bf(o2 - bf2f(h2)), f2bf(o3 - bf2f(h3)));
}

// ---------------- segment ranges from sorted image_ids -----------------------
__global__ void seg_kernel(const int* __restrict__ ids, int2* __restrict__ segs)
{
  int i = blockIdx.x * 256 + threadIdx.x;
  int b = blockIdx.y;
  const int* row = ids + b * SEQ;
  int v = row[i];
  int lo = 0, hi = SEQ;
  while (lo < hi){ int mid = (lo + hi) >> 1; if (row[mid] <  v) lo = mid + 1; else hi = mid; }
  int s = lo;
  lo = 0; hi = SEQ;
  while (lo < hi){ int mid = (lo + hi) >> 1; if (row[mid] <= v) lo = mid + 1; else hi = mid; }
  segs[b * SEQ + i] = make_int2(s, lo);
}

// --------- MFMA flash attention over segments -------------------------------
// block = (b,h) x 64-q tile; 4 waves x 16 q-rows; 32-key tiles in LDS.
// QK^T swapped (mfma(K,Q), 3-product split) -> q lane-local softmax;
// O^T = mfma(V^T, P). K LDS XOR-swizzled; V^T LDS pad-40 rows.
__global__ __launch_bounds__(256) void attn_kernel(
    const float* __restrict__ qb, const float* __restrict__ kb,
    const ushort_t* __restrict__ vt, const int2* __restrict__ segs,
    ushort_t* __restrict__ oh, ushort_t* __restrict__ ol)
{
  __shared__ ushort_t Kh[32 * 64];
  __shared__ ushort_t Kl[32 * 64];
  __shared__ ushort_t Vl[64 * 40];

  const int tid = threadIdx.x;
  const int w = tid >> 6, lane = tid & 63;
  const int q15 = lane & 15, kg = lane >> 4;
  const int bh = blockIdx.x, b = bh / 12, h = bh % 12;
  const int qt = blockIdx.y;
  const int qrow = qt * 64 + w * 16 + q15;
  const size_t qtok = (size_t)b * SEQ + qrow;

  // Q fragments (hi/lo split), col=lane&15=q, k=d
  bf16x8 qfh[2], qfl[2];
  {
    const float* qp = qb + qtok * DIM + h * 64 + kg * 8;
    #pragma unroll
    for (int dh2 = 0; dh2 < 2; dh2++){
      float4 v0 = *(const float4*)(qp + dh2 * 32);
      float4 v1 = *(const float4*)(qp + dh2 * 32 + 4);
      float f[8] = {v0.x, v0.y, v0.z, v0.w, v1.x, v1.y, v1.z, v1.w};
      unsigned uh[4], ul[4];
      #pragma unroll
      for (int j = 0; j < 4; j++){
        ushort_t h0 = f2bf(f[2*j]), h1 = f2bf(f[2*j+1]);
        uh[j] = (unsigned)h0 | ((unsigned)h1 << 16);
        ul[j] = (unsigned)f2bf(f[2*j] - bf2f(h0)) | ((unsigned)f2bf(f[2*j+1] - bf2f(h1)) << 16);
      }
      qfh[dh2] = __builtin_bit_cast(bf16x8, make_uint4(uh[0], uh[1], uh[2], uh[3]));
      qfl[dh2] = __builtin_bit_cast(bf16x8, make_uint4(ul[0], ul[1], ul[2], ul[3]));
    }
  }

  const int2 se  = segs[qtok];
  const int2 se0 = segs[(size_t)b * SEQ + qt * 64];
  const int2 se1 = segs[(size_t)b * SEQ + qt * 64 + 63];
  const int klo = se0.x & ~31, khi = se1.y;

  float m = -3.0e38f, l = 0.f;
  f32x4 oacc[4] = {};

  // staging indices
  const int krl = tid >> 3, dsl = tid & 7;          // K: 32 rows x 8 d-slots
  const int vd = tid >> 2, vko = (tid & 3) * 8;     // V: 64 d x 4 k-slots

  for (int kt = klo; kt < khi; kt += 32){
    // ---- stage K tile (f32 -> bf16 hi/lo, XOR-swizzled) ----
    {
      int krow = kt + krl; if (krow > SEQ - 1) krow = SEQ - 1;
      const float* kp = kb + ((size_t)b * SEQ + krow) * DIM + h * 64 + dsl * 8;
      float4 a = *(const float4*)kp, c = *(const float4*)(kp + 4);
      float f[8] = {a.x, a.y, a.z, a.w, c.x, c.y, c.z, c.w};
      unsigned uh[4], ul[4];
      #pragma unroll
      for (int j = 0; j < 4; j++){
        ushort_t h0 = f2bf(f[2*j]), h1 = f2bf(f[2*j+1]);
        uh[j] = (unsigned)h0 | ((unsigned)h1 << 16);
        ul[j] = (unsigned)f2bf(f[2*j] - bf2f(h0)) | ((unsigned)f2bf(f[2*j+1] - bf2f(h1)) << 16);
      }
      unsigned off = ((unsigned)krl << 7) + ((unsigned)dsl << 4);
      off ^= (unsigned)(krl & 7) << 4;
      *(uint4*)((char*)Kh + off) = make_uint4(uh[0], uh[1], uh[2], uh[3]);
      *(uint4*)((char*)Kl + off) = make_uint4(ul[0], ul[1], ul[2], ul[3]);
      // ---- stage V^T tile (bf16, rows of 32 keys, stride 40) ----
      int ksrc = kt + vko; if (ksrc > SEQ - 8) ksrc = SEQ - 8;
      uint4 vv = *(const uint4*)(vt + ((size_t)bh * 64 + vd) * SEQ + ksrc);
      *(uint4*)((char*)Vl + vd * 80 + vko * 2) = vv;
    }
    __syncthreads();

    // ---- QK^T: S[key][q], 3-product split ----
    f32x4 s[2] = {};
    #pragma unroll
    for (int dh2 = 0; dh2 < 2; dh2++){
      #pragma unroll
      for (int khf = 0; khf < 2; khf++){
        int row = khf * 16 + q15;
        unsigned off = ((unsigned)row << 7) + ((unsigned)(dh2 * 4 + kg) << 4);
        off ^= (unsigned)(row & 7) << 4;
        bf16x8 kfh = *(const bf16x8*)((const char*)Kh + off);
        bf16x8 kfl = *(const bf16x8*)((const char*)Kl + off);
        s[khf] = __builtin_amdgcn_mfma_f32_16x16x32_bf16(kfl, qfh[dh2], s[khf], 0, 0, 0);
        s[khf] = __builtin_amdgcn_mfma_f32_16x16x32_bf16(kfh, qfl[dh2], s[khf], 0, 0, 0);
        s[khf] = __builtin_amdgcn_mfma_f32_16x16x32_bf16(kfh, qfh[dh2], s[khf], 0, 0, 0);
      }
    }

    // ---- online softmax (q = lane-local) ----
    float p[8]; float tmax = -3.0e38f;
    #pragma unroll
    for (int khf = 0; khf < 2; khf++)
      #pragma unroll
      for (int i = 0; i < 4; i++){
        int key = kt + khf * 16 + kg * 4 + i;
        bool val = (key >= se.x) && (key < se.y);
        float sv = val ? s[khf][i] : -3.0e38f;
        p[khf * 4 + i] = sv;
        tmax = fmaxf(tmax, sv);
      }
    tmax = fmaxf(tmax, __shfl_xor(tmax, 16));
    tmax = fmaxf(tmax, __shfl_xor(tmax, 32));
    float mnew = fmaxf(m, tmax);
    float sc = __expf(m - mnew);
    float psum = 0.f;
    #pragma unroll
    for (int j = 0; j < 8; j++){
      float pv = (p[j] > -1.0e38f) ? __expf(p[j] - mnew) : 0.f;
      p[j] = pv; psum += pv;
    }
    psum += __shfl_xor(psum, 16);
    psum += __shfl_xor(psum, 32);
    l = l * sc + psum;
    m = mnew;
    #pragma unroll
    for (int dt = 0; dt < 4; dt++) oacc[dt] *= sc;

    // ---- P -> B-frag (pack bf16 + 8 shfls) ----
    unsigned u00 = pk2(p[0], p[1]), u01 = pk2(p[2], p[3]);
    unsigned u10 = pk2(p[4], p[5]), u11 = pk2(p[6], p[7]);
    int s0l = q15 + ((kg & 1) << 5);
    int s1l = s0l + 16;
    unsigned a0 = __shfl(u00, s0l), b0 = __shfl(u01, s0l);
    unsigned a1 = __shfl(u00, s1l), b1 = __shfl(u01, s1l);
    unsigned c0 = __shfl(u10, s0l), d0 = __shfl(u11, s0l);
    unsigned c1 = __shfl(u10, s1l), d1 = __shfl(u11, s1l);
    bool hih = kg >= 2;
    bf16x8 pfrag = __builtin_bit_cast(bf16x8,
        make_uint4(hih ? c0 : a0, hih ? d0 : b0, hih ? c1 : a1, hih ? d1 : b1));

    // ---- O^T += V^T @ P ----
    #pragma unroll
    for (int dt = 0; dt < 4; dt++){
      bf16x8 vf = *(const bf16x8*)((const char*)Vl + (dt * 16 + q15) * 80 + kg * 16);
      oacc[dt] = __builtin_amdgcn_mfma_f32_16x16x32_bf16(vf, pfrag, oacc[dt], 0, 0, 0);
    }
    __syncthreads();
  }

  // ---- epilogue: O = O^T/l, write hi/lo ----
  float rl = 1.f / l;
  size_t obase = qtok * DIM + h * 64;
  #pragma unroll
  for (int dt = 0; dt < 4; dt++){
    ushort4 hs, ls;
    float v0 = oacc[dt][0] * rl, v1 = oacc[dt][1] * rl;
    float v2 = oacc[dt][2] * rl, v3 = oacc[dt][3] * rl;
    hs.x = f2bf(v0); ls.x = f2bf(v0 - bf2f(hs.x));
    hs.y = f2bf(v1); ls.y = f2bf(v1 - bf2f(hs.y));
    hs.z = f2bf(v2); ls.z = f2bf(v2 - bf2f(hs.z));
    hs.w = f2bf(v3); ls.w = f2bf(v3 - bf2f(hs.w));
    *(ushort4*)(oh + obase + dt * 16 + kg * 4) = hs;
    *(ushort4*)(ol + obase + dt * 16 + kg * 4) = ls;
  }
}

// ---------------- driver -----------------------------------------------------
extern "C" void kernel_launch(void* const* d_in, const int* in_sizes, int n_in,
                              void* d_out, int out_size, void* d_ws, size_t ws_size,
                              hipStream_t stream)
{
  const float* patches   = (const float*)d_in[0];
  const int*   h_idx     = (const int*)d_in[1];
  const int*   w_idx     = (const int*)d_in[2];
  const int*   image_ids = (const int*)d_in[3];
  const float* pos_h = (const float*)d_in[4];
  const float* pos_w = (const float*)d_in[5];
  const float* Wp  = (const float*)d_in[6];
  const float* bp  = (const float*)d_in[7];
  const float* lnp = (const float*)d_in[8];
  const float* ln1 = (const float*)d_in[9];
  const float* qg  = (const float*)d_in[10];
  const float* kg  = (const float*)d_in[11];
  const float* Wq  = (const float*)d_in[12];
  const float* Wkv = (const float*)d_in[13];
  const float* Wo  = (const float*)d_in[14];
  const float* ln2 = (const float*)d_in[15];
  const float* W1  = (const float*)d_in[16];
  const float* b1  = (const float*)d_in[17];
  const float* W2  = (const float*)d_in[18];
  const float* b2  = (const float*)d_in[19];
  const float* lnf = (const float*)d_in[20];
  float* out = (float*)d_out;

  float* ws = (float*)d_ws;
  float* x    = ws;                      // 2048*768 f32
  float* q    = x + NTOK * DIM;          // 2048*768 f32
  float* kbuf = q + NTOK * DIM;          // 2048*768 f32 (k only)
  ushort_t* aAh = (ushort_t*)(kbuf + NTOK * DIM);
  ushort_t* aAl = aAh + NTOK * DIM;
  ushort_t* aBh = aAl + NTOK * DIM;
  ushort_t* aBl = aBh + NTOK * MLP_;
  ushort_t* wth = aBl + NTOK * MLP_;
  ushort_t* wtl = wth + WELTS;
  ushort_t* vtb = wtl + WELTS;           // 24*64*1024 bf16 V^T
  int2* segs = (int2*)(vtb + 24 * 64 * SEQ);

  seg_kernel<<<dim3(4, 2), 256, 0, stream>>>(image_ids, segs);
  posadd_kernel<<<1536, 256, 0, stream>>>(patches, h_idx, w_idx, pos_h, pos_w, aAh, aAl);
  convert_w_kernel<<<288, 256, 0, stream>>>(Wp, nullptr, nullptr, nullptr, nullptr, 0, 1, wth, wtl);
  gemm_kernel<<<dim3(12, 32), 512, 0, stream>>>(
      aAh, aAl, wth, wtl, bp, nullptr, q, nullptr, nullptr, nullptr, NTOK, DIM, DIM, 0);
  ln_kernel<<<NTOK / 4, 256, 0, stream>>>(q, lnp, x, nullptr, nullptr);

  for (int i = 0; i < 8; i++){
    convert_w_kernel<<<3456, 256, 0, stream>>>(Wq, Wkv, Wo, W1, W2, i, 0, wth, wtl);
    ln_kernel<<<NTOK / 4, 256, 0, stream>>>(x, ln1 + i * DIM, nullptr, aAh, aAl);
    gemm_kernel<<<dim3(12, 32), 512, 0, stream>>>(
        aAh, aAl, wth + 0, wtl + 0, nullptr, nullptr, q, nullptr, nullptr, nullptr,
        NTOK, DIM, DIM, 0);
    gemm_kernel<<<dim3(24, 32), 512, 0, stream>>>(
        aAh, aAl, wth + 589824, wtl + 589824, nullptr, nullptr, kbuf, nullptr, nullptr, vtb,
        NTOK, 2 * DIM, DIM, 2);
    rms_kernel<<<12288, 256, 0, stream>>>(q, kbuf, qg + i * HEADS * DH, kg + i * HEADS * DH);
    attn_kernel<<<dim3(24, 16), 256, 0, stream>>>(q, kbuf, vtb, segs, aAh, aAl);
    gemm_kernel<<<dim3(12, 32), 512, 0, stream>>>(
        aAh, aAl, wth + 1769472, wtl + 1769472, nullptr, x, x, nullptr, nullptr, nullptr,
        NTOK, DIM, DIM, 0);
    ln_kernel<<<NTOK / 4, 256, 0, stream>>>(x, ln2 + i * DIM, nullptr, aAh, aAl);
    gemm_kernel<<<dim3(48, 32), 512, 0, stream>>>(
        aAh, aAl, wth + 2359296, wtl + 2359296, b1 + i * MLP_, nullptr,
        nullptr, aBh, aBl, nullptr, NTOK, MLP_, DIM, 1);
    gemm_kernel<<<dim3(12, 32), 512, 0, stream>>>(
        aBh, aBl, wth + 4718592, wtl + 4718592, b2 + i * DIM, x, x, nullptr, nullptr, nullptr,
        NTOK, DIM, MLP_, 0);
  }
  ln_kernel<<<NTOK / 4, 256, 0, stream>>>(x, lnf, out, nullptr, nullptr);
}

// Round 5
// 1525.885 us; speedup vs baseline: 2.7102x; 1.2575x over previous
//
#include <hip/hip_runtime.h>
#include <hip/hip_bf16.h>
#include <math.h>

typedef _Float16 f16;
typedef f16   f16x8 __attribute__((ext_vector_type(8)));
typedef float f32x4 __attribute__((ext_vector_type(4)));
typedef unsigned short ushort_t;

#define DIM   768
#define HEADS 12
#define DH    64
#define MLP_  3072
#define NTOK  2048
#define SEQ   1024
#define WELTS 7077888   // per-layer converted weight elements (Wq+Wkv+Wo+W1+W2)

__device__ __forceinline__ ushort_t h2u(f16 h){ return __builtin_bit_cast(ushort_t, h); }
__device__ __forceinline__ unsigned pk2h(float a, float b){
  return (unsigned)h2u((f16)a) | ((unsigned)h2u((f16)b) << 16);
}
__device__ __forceinline__ void gload16(const void* g, void* l){
  __builtin_amdgcn_global_load_lds(
      (const __attribute__((address_space(1))) void*)g,
      (__attribute__((address_space(3))) void*)l, 16, 0, 0);
}
__device__ __forceinline__ float wred_sum(float v){
  #pragma unroll
  for (int o = 32; o > 0; o >>= 1) v += __shfl_xor(v, o);
  return v;
}

// ---------- weight convert: W[K][N] f32 -> Wt_h/Wt_l [N][K] f16 --------------
__global__ __launch_bounds__(256) void convert_w_kernel(
    const float* __restrict__ Wq, const float* __restrict__ Wkv,
    const float* __restrict__ Wo, const float* __restrict__ W1,
    const float* __restrict__ W2, int layer, int wp_only,
    f16* __restrict__ th, f16* __restrict__ tl)
{
  int bid = blockIdx.x;
  const float* src; int K, N; size_t ooff; int t;
  if (wp_only){ src = Wq; K = 768; N = 768; ooff = 0; t = bid; }
  else if (bid < 288) { src = Wq;  K = 768;  N = 768;  ooff = 0;       t = bid; }
  else if (bid < 864) { src = Wkv; K = 768;  N = 1536; ooff = 589824;  t = bid - 288; }
  else if (bid < 1152){ src = Wo;  K = 768;  N = 768;  ooff = 1769472; t = bid - 864; }
  else if (bid < 2304){ src = W1;  K = 768;  N = 3072; ooff = 2359296; t = bid - 1152; }
  else                { src = W2;  K = 3072; N = 768;  ooff = 4718592; t = bid - 2304; }
  if (!wp_only) src += (size_t)layer * K * N;
  int ntn = N >> 6;
  int tk = t / ntn, tn = t % ntn;
  int k0 = tk * 32, n0 = tn * 64;

  __shared__ ushort_t lh[32][66];
  __shared__ ushort_t ll[32][66];
  int tid = threadIdx.x;
  #pragma unroll
  for (int rr = 0; rr < 2; rr++){
    int k = rr * 16 + (tid >> 4);
    int n = (tid & 15) * 4;
    float4 v = *(const float4*)(src + (size_t)(k0 + k) * N + n0 + n);
    f16 h0 = (f16)v.x, h1 = (f16)v.y, h2 = (f16)v.z, h3 = (f16)v.w;
    lh[k][n+0] = h2u(h0); ll[k][n+0] = h2u((f16)(v.x - (float)h0));
    lh[k][n+1] = h2u(h1); ll[k][n+1] = h2u((f16)(v.y - (float)h1));
    lh[k][n+2] = h2u(h2); ll[k][n+2] = h2u((f16)(v.z - (float)h2));
    lh[k][n+3] = h2u(h3); ll[k][n+3] = h2u((f16)(v.w - (float)h3));
  }
  __syncthreads();
  int n = tid >> 2, kq = tid & 3;
  unsigned ph[4], pl[4];
  #pragma unroll
  for (int j = 0; j < 4; j++){
    ph[j] = (unsigned)lh[kq*8 + 2*j][n] | ((unsigned)lh[kq*8 + 2*j + 1][n] << 16);
    pl[j] = (unsigned)ll[kq*8 + 2*j][n] | ((unsigned)ll[kq*8 + 2*j + 1][n] << 16);
  }
  size_t obase = ooff + (size_t)(n0 + n) * K + k0 + kq * 8;
  *(uint4*)(th + obase) = make_uint4(ph[0], ph[1], ph[2], ph[3]);
  *(uint4*)(tl + obase) = make_uint4(pl[0], pl[1], pl[2], pl[3]);
}

// ---------------- GEMM: C[M,N] = epi(Aq[M,K] @ (Wh+Wl)[N,K]^T) ---------------
// A single fp16, W split fp16 hi/lo, 2 MFMA products. BM=128 BN=64 BK=64,
// 4 waves (2x2 of 64x32). XOR-swizzled LDS (pre-swizzled global source).
// mode 0: f32 out (+bias)(+res); mode 1: f16 out of gelu(acc+bias);
// mode 2 (kv): col<768 -> f32 k-buffer (stride 768); col>=768 -> Vt f16 transposed.
__global__ __launch_bounds__(256) void gemm_kernel(
    const f16* __restrict__ Aq, const f16* __restrict__ Bh, const f16* __restrict__ Bl,
    const float* __restrict__ bias, const float* __restrict__ res,
    float* __restrict__ C, f16* __restrict__ Cq, f16* __restrict__ Vt,
    int N, int K, int nbx, int mode)
{
  __shared__ __align__(16) f16 sA[128 * 64];
  __shared__ __align__(16) f16 sBh[64 * 64];
  __shared__ __align__(16) f16 sBl[64 * 64];
  const int tid = threadIdx.x;
  const int wid = tid >> 6, lane = tid & 63;
  // XCD-chunked swizzle, row(M)-fastest decode: B col-panel L2-resident per XCD
  const int nwg = nbx << 4;
  const int bid = blockIdx.x;
  const int swz = (bid & 7) * (nwg >> 3) + (bid >> 3);
  const int by = swz & 15, bx = swz >> 4;
  const int brow = by << 7, bcol = bx << 6;
  const int wr = (wid >> 1) << 6, wc = (wid & 1) << 5;
  const int fr = lane & 15, fq = lane >> 4;

  f32x4 acc[4][2] = {};
  const int nk = K >> 6;

  for (int ks = 0; ks < nk; ks++){
    const int k0 = ks << 6;
    if (ks) __syncthreads();
    #pragma unroll
    for (int i = 0; i < 4; i++){
      int idx = tid + i * 256;
      int r = idx >> 3, c = idx & 7;
      int gc = c ^ (r & 7);
      gload16(Aq + (size_t)(brow + r) * K + k0 + gc * 8, sA + idx * 8);
    }
    #pragma unroll
    for (int i = 0; i < 2; i++){
      int idx = tid + i * 256;
      int r = idx >> 3, c = idx & 7;
      int gc = c ^ (r & 7);
      gload16(Bh + (size_t)(bcol + r) * K + k0 + gc * 8, sBh + idx * 8);
      gload16(Bl + (size_t)(bcol + r) * K + k0 + gc * 8, sBl + idx * 8);
    }
    __syncthreads();
    #pragma unroll
    for (int s = 0; s < 2; s++){
      f16x8 a[4], bh[2], bl[2];
      #pragma unroll
      for (int m = 0; m < 4; m++){
        int r = wr + m * 16 + fr;
        int ch = (s * 4 + fq) ^ (r & 7);
        a[m] = *(const f16x8*)(sA + r * 64 + ch * 8);
      }
      #pragma unroll
      for (int n = 0; n < 2; n++){
        int r = wc + n * 16 + fr;
        int ch = (s * 4 + fq) ^ (r & 7);
        bh[n] = *(const f16x8*)(sBh + r * 64 + ch * 8);
        bl[n] = *(const f16x8*)(sBl + r * 64 + ch * 8);
      }
      #pragma unroll
      for (int m = 0; m < 4; m++)
        #pragma unroll
        for (int n = 0; n < 2; n++){
          acc[m][n] = __builtin_amdgcn_mfma_f32_16x16x32_f16(a[m], bl[n], acc[m][n], 0, 0, 0);
          acc[m][n] = __builtin_amdgcn_mfma_f32_16x16x32_f16(a[m], bh[n], acc[m][n], 0, 0, 0);
        }
    }
  }

  // epilogue: D layout col=lane&15, row=(lane>>4)*4+i
  #pragma unroll
  for (int n = 0; n < 2; n++){
    int col = bcol + wc + n * 16 + fr;
    float bv = bias ? bias[col] : 0.f;
    #pragma unroll
    for (int m = 0; m < 4; m++){
      int row0 = brow + wr + m * 16 + (fq << 2);
      if (mode == 2){
        if (col < 768){
          #pragma unroll
          for (int i = 0; i < 4; i++)
            C[(size_t)(row0 + i) * 768 + col] = acc[m][n][i];
        } else {
          int hcol = col - 768, hh = hcol >> 6, dd = hcol & 63;
          int bq = row0 >> 10, tok0 = row0 & 1023;
          ushort4 sv;
          sv.x = h2u((f16)acc[m][n][0]); sv.y = h2u((f16)acc[m][n][1]);
          sv.z = h2u((f16)acc[m][n][2]); sv.w = h2u((f16)acc[m][n][3]);
          *(ushort4*)(Vt + ((size_t)((bq * 12 + hh) * 64 + dd)) * 1024 + tok0) = sv;
        }
      } else if (mode == 1){
        #pragma unroll
        for (int i = 0; i < 4; i++){
          float v = acc[m][n][i] + bv;
          float ge = 0.5f * v * (1.f + erff(v * 0.70710678118654752f));
          Cq[(size_t)(row0 + i) * N + col] = (f16)ge;
        }
      } else {
        #pragma unroll
        for (int i = 0; i < 4; i++){
          float v = acc[m][n][i] + bv;
          size_t o = (size_t)(row0 + i) * N + col;
          if (res) v += res[o];
          C[o] = v;
        }
      }
    }
  }
}

// ---------------- LayerNorm; out = f32 (yf) or f16 (yq) ----------------------
__global__ __launch_bounds__(256) void ln_kernel(
    const float* __restrict__ x, const float* __restrict__ g,
    float* __restrict__ yf, f16* __restrict__ yq)
{
  int wid = threadIdx.x >> 6, lane = threadIdx.x & 63;
  int row = blockIdx.x * 4 + wid;
  const float* xr = x + (size_t)row * DIM;
  float v[12]; float s = 0.f;
  #pragma unroll
  for (int d = 0; d < 12; d++){ v[d] = xr[d * 64 + lane]; s += v[d]; }
  s = wred_sum(s);
  float mean = s * (1.f / 768.f);
  float q = 0.f;
  #pragma unroll
  for (int d = 0; d < 12; d++){ float t = v[d] - mean; q += t * t; }
  q = wred_sum(q);
  float rstd = rsqrtf(q * (1.f / 768.f) + 1e-5f);
  size_t base = (size_t)row * DIM;
  #pragma unroll
  for (int d = 0; d < 12; d++){
    float y = (v[d] - mean) * rstd * g[d * 64 + lane];
    if (yf) yf[base + d * 64 + lane] = y;
    else    yq[base + d * 64 + lane] = (f16)y;
  }
}

// ------------- fused qk rmsnorm for q and k buffers, in-place ----------------
__global__ __launch_bounds__(256) void rms_kernel(
    float* __restrict__ q, float* __restrict__ kb,
    const float* __restrict__ qg, const float* __restrict__ kg)
{
  int wid = threadIdx.x >> 6, lane = threadIdx.x & 63;
  int id = blockIdx.x * 4 + wid;
  float* p; const float* g;
  int id2 = id < 24576 ? id : id - 24576;
  int tok = id2 / HEADS, h = id2 % HEADS;
  if (id < 24576){ p = q  + (size_t)tok * DIM + h * 64; g = qg + h * 64; }
  else           { p = kb + (size_t)tok * DIM + h * 64; g = kg + h * 64; }
  float v = p[lane];
  float n2 = wred_sum(v * v);
  float nn = fmaxf(sqrtf(n2), 1e-12f);
  p[lane] = v * (8.f / nn) * g[lane];
}

// ---------------- pos-embed add -> f16 ---------------------------------------
__global__ __launch_bounds__(256) void posadd_kernel(
    const float* __restrict__ patches, const int* __restrict__ hi,
    const int* __restrict__ wi, const float* __restrict__ ph,
    const float* __restrict__ pw, f16* __restrict__ oq)
{
  int idx = blockIdx.x * 256 + threadIdx.x;
  int tok = idx / 192, cv = idx % 192;
  float4 p = ((const float4*)patches)[idx];
  float4 a = *(const float4*)(ph + (size_t)hi[tok] * DIM + cv * 4);
  float4 b = *(const float4*)(pw + (size_t)wi[tok] * DIM + cv * 4);
  ushort4 o;
  o.x = h2u((f16)(p.x + a.x + b.x)); o.y = h2u((f16)(p.y + a.y + b.y));
  o.z = h2u((f16)(p.z + a.z + b.z)); o.w = h2u((f16)(p.w + a.w + b.w));
  ((ushort4*)oq)[idx] = o;
}

// ---------------- segment ranges from sorted image_ids -----------------------
__global__ void seg_kernel(const int* __restrict__ ids, int2* __restrict__ segs)
{
  int i = blockIdx.x * 256 + threadIdx.x;
  int b = blockIdx.y;
  const int* row = ids + b * SEQ;
  int v = row[i];
  int lo = 0, hi = SEQ;
  while (lo < hi){ int mid = (lo + hi) >> 1; if (row[mid] <  v) lo = mid + 1; else hi = mid; }
  int s = lo;
  lo = 0; hi = SEQ;
  while (lo < hi){ int mid = (lo + hi) >> 1; if (row[mid] <= v) lo = mid + 1; else hi = mid; }
  segs[b * SEQ + i] = make_int2(s, lo);
}

// --------- MFMA flash attention over segments (all-f16 single product) -------
__global__ __launch_bounds__(256) void attn_kernel(
    const float* __restrict__ qb, const float* __restrict__ kb,
    const f16* __restrict__ vt, const int2* __restrict__ segs,
    f16* __restrict__ oq)
{
  __shared__ ushort_t Kq[32 * 64];
  __shared__ ushort_t Vl[64 * 40];

  const int tid = threadIdx.x;
  const int w = tid >> 6, lane = tid & 63;
  const int q15 = lane & 15, kg = lane >> 4;
  const int bh = blockIdx.x, b = bh / 12, h = bh % 12;
  const int qt = blockIdx.y;
  const int qrow = qt * 64 + w * 16 + q15;
  const size_t qtok = (size_t)b * SEQ + qrow;

  // Q fragments (f16), col=lane&15=q, k=d
  f16x8 qf[2];
  {
    const float* qp = qb + qtok * DIM + h * 64 + kg * 8;
    #pragma unroll
    for (int dh2 = 0; dh2 < 2; dh2++){
      float4 v0 = *(const float4*)(qp + dh2 * 32);
      float4 v1 = *(const float4*)(qp + dh2 * 32 + 4);
      f16x8 f;
      f[0] = (f16)v0.x; f[1] = (f16)v0.y; f[2] = (f16)v0.z; f[3] = (f16)v0.w;
      f[4] = (f16)v1.x; f[5] = (f16)v1.y; f[6] = (f16)v1.z; f[7] = (f16)v1.w;
      qf[dh2] = f;
    }
  }

  const int2 se  = segs[qtok];
  const int2 se0 = segs[(size_t)b * SEQ + qt * 64];
  const int2 se1 = segs[(size_t)b * SEQ + qt * 64 + 63];
  const int klo = se0.x & ~31, khi = se1.y;

  float m = -3.0e38f, l = 0.f;
  f32x4 oacc[4] = {};

  const int krl = tid >> 3, dsl = tid & 7;          // K: 32 rows x 8 d-slots
  const int vd = tid >> 2, vko = (tid & 3) * 8;     // V: 64 d x 4 k-slots

  for (int kt = klo; kt < khi; kt += 32){
    // ---- stage K tile (f32 -> f16, XOR-swizzled) ----
    {
      int krow = kt + krl; if (krow > SEQ - 1) krow = SEQ - 1;
      const float* kp = kb + ((size_t)b * SEQ + krow) * DIM + h * 64 + dsl * 8;
      float4 a = *(const float4*)kp, c = *(const float4*)(kp + 4);
      unsigned u0 = pk2h(a.x, a.y), u1 = pk2h(a.z, a.w);
      unsigned u2 = pk2h(c.x, c.y), u3 = pk2h(c.z, c.w);
      unsigned off = ((unsigned)krl << 7) + ((unsigned)dsl << 4);
      off ^= (unsigned)(krl & 7) << 4;
      *(uint4*)((char*)Kq + off) = make_uint4(u0, u1, u2, u3);
      // ---- stage V^T tile (f16 rows of 32 keys, stride 40) ----
      int ksrc = kt + vko; if (ksrc > SEQ - 8) ksrc = SEQ - 8;
      uint4 vv = *(const uint4*)(vt + ((size_t)bh * 64 + vd) * SEQ + ksrc);
      *(uint4*)((char*)Vl + vd * 80 + vko * 2) = vv;
    }
    __syncthreads();

    // ---- QK^T: S[key][q] ----
    f32x4 s[2] = {};
    #pragma unroll
    for (int dh2 = 0; dh2 < 2; dh2++){
      #pragma unroll
      for (int khf = 0; khf < 2; khf++){
        int row = khf * 16 + q15;
        unsigned off = ((unsigned)row << 7) + ((unsigned)(dh2 * 4 + kg) << 4);
        off ^= (unsigned)(row & 7) << 4;
        f16x8 kf = *(const f16x8*)((const char*)Kq + off);
        s[khf] = __builtin_amdgcn_mfma_f32_16x16x32_f16(kf, qf[dh2], s[khf], 0, 0, 0);
      }
    }

    // ---- online softmax (q lane-local) ----
    float p[8]; float tmax = -3.0e38f;
    #pragma unroll
    for (int khf = 0; khf < 2; khf++)
      #pragma unroll
      for (int i = 0; i < 4; i++){
        int key = kt + khf * 16 + kg * 4 + i;
        bool val = (key >= se.x) && (key < se.y);
        float sv = val ? s[khf][i] : -3.0e38f;
        p[khf * 4 + i] = sv;
        tmax = fmaxf(tmax, sv);
      }
    tmax = fmaxf(tmax, __shfl_xor(tmax, 16));
    tmax = fmaxf(tmax, __shfl_xor(tmax, 32));
    float mnew = fmaxf(m, tmax);
    float sc = __expf(m - mnew);
    float psum = 0.f;
    #pragma unroll
    for (int j = 0; j < 8; j++){
      float pv = (p[j] > -1.0e38f) ? __expf(p[j] - mnew) : 0.f;
      p[j] = pv; psum += pv;
    }
    psum += __shfl_xor(psum, 16);
    psum += __shfl_xor(psum, 32);
    l = l * sc + psum;
    m = mnew;
    #pragma unroll
    for (int dt = 0; dt < 4; dt++) oacc[dt] *= sc;

    // ---- P -> B-frag (pack f16 + 8 shfls) ----
    unsigned u00 = pk2h(p[0], p[1]), u01 = pk2h(p[2], p[3]);
    unsigned u10 = pk2h(p[4], p[5]), u11 = pk2h(p[6], p[7]);
    int s0l = q15 + ((kg & 1) << 5);
    int s1l = s0l + 16;
    unsigned a0 = __shfl(u00, s0l), b0 = __shfl(u01, s0l);
    unsigned a1 = __shfl(u00, s1l), b1 = __shfl(u01, s1l);
    unsigned c0 = __shfl(u10, s0l), d0 = __shfl(u11, s0l);
    unsigned c1 = __shfl(u10, s1l), d1 = __shfl(u11, s1l);
    bool hih = kg >= 2;
    f16x8 pfrag = __builtin_bit_cast(f16x8,
        make_uint4(hih ? c0 : a0, hih ? d0 : b0, hih ? c1 : a1, hih ? d1 : b1));

    // ---- O^T += V^T @ P ----
    #pragma unroll
    for (int dt = 0; dt < 4; dt++){
      f16x8 vf = *(const f16x8*)((const char*)Vl + (dt * 16 + q15) * 80 + kg * 16);
      oacc[dt] = __builtin_amdgcn_mfma_f32_16x16x32_f16(vf, pfrag, oacc[dt], 0, 0, 0);
    }
    __syncthreads();
  }

  // ---- epilogue: O = O^T/l, f16 out ----
  float rl = 1.f / l;
  size_t obase = qtok * DIM + h * 64;
  #pragma unroll
  for (int dt = 0; dt < 4; dt++){
    ushort4 hs;
    hs.x = h2u((f16)(oacc[dt][0] * rl)); hs.y = h2u((f16)(oacc[dt][1] * rl));
    hs.z = h2u((f16)(oacc[dt][2] * rl)); hs.w = h2u((f16)(oacc[dt][3] * rl));
    *(ushort4*)(oq + obase + dt * 16 + kg * 4) = hs;
  }
}

// ---------------- driver -----------------------------------------------------
extern "C" void kernel_launch(void* const* d_in, const int* in_sizes, int n_in,
                              void* d_out, int out_size, void* d_ws, size_t ws_size,
                              hipStream_t stream)
{
  const float* patches   = (const float*)d_in[0];
  const int*   h_idx     = (const int*)d_in[1];
  const int*   w_idx     = (const int*)d_in[2];
  const int*   image_ids = (const int*)d_in[3];
  const float* pos_h = (const float*)d_in[4];
  const float* pos_w = (const float*)d_in[5];
  const float* Wp  = (const float*)d_in[6];
  const float* bp  = (const float*)d_in[7];
  const float* lnp = (const float*)d_in[8];
  const float* ln1 = (const float*)d_in[9];
  const float* qg  = (const float*)d_in[10];
  const float* kg  = (const float*)d_in[11];
  const float* Wq  = (const float*)d_in[12];
  const float* Wkv = (const float*)d_in[13];
  const float* Wo  = (const float*)d_in[14];
  const float* ln2 = (const float*)d_in[15];
  const float* W1  = (const float*)d_in[16];
  const float* b1  = (const float*)d_in[17];
  const float* W2  = (const float*)d_in[18];
  const float* b2  = (const float*)d_in[19];
  const float* lnf = (const float*)d_in[20];
  float* out = (float*)d_out;

  float* ws = (float*)d_ws;
  float* x    = ws;                      // 2048*768 f32
  float* q    = x + NTOK * DIM;          // 2048*768 f32
  float* kbuf = q + NTOK * DIM;          // 2048*768 f32 (k only)
  int2* segs = (int2*)(kbuf + NTOK * DIM);
  f16* aAq = (f16*)(segs + NTOK);        // 2048*768
  f16* aBq = aAq + NTOK * DIM;           // 2048*3072
  f16* wth = aBq + NTOK * MLP_;          // WELTS
  f16* wtl = wth + WELTS;
  f16* vtb = wtl + WELTS;                // 24*64*1024 V^T

  seg_kernel<<<dim3(4, 2), 256, 0, stream>>>(image_ids, segs);
  posadd_kernel<<<1536, 256, 0, stream>>>(patches, h_idx, w_idx, pos_h, pos_w, aAq);
  convert_w_kernel<<<288, 256, 0, stream>>>(Wp, nullptr, nullptr, nullptr, nullptr, 0, 1, wth, wtl);
  gemm_kernel<<<192, 256, 0, stream>>>(
      aAq, wth, wtl, bp, nullptr, q, nullptr, nullptr, DIM, DIM, 12, 0);
  ln_kernel<<<NTOK / 4, 256, 0, stream>>>(q, lnp, x, nullptr);

  for (int i = 0; i < 8; i++){
    convert_w_kernel<<<3456, 256, 0, stream>>>(Wq, Wkv, Wo, W1, W2, i, 0, wth, wtl);
    ln_kernel<<<NTOK / 4, 256, 0, stream>>>(x, ln1 + i * DIM, nullptr, aAq);
    gemm_kernel<<<192, 256, 0, stream>>>(
        aAq, wth + 0, wtl + 0, nullptr, nullptr, q, nullptr, nullptr,
        DIM, DIM, 12, 0);
    gemm_kernel<<<384, 256, 0, stream>>>(
        aAq, wth + 589824, wtl + 589824, nullptr, nullptr, kbuf, nullptr, vtb,
        2 * DIM, DIM, 24, 2);
    rms_kernel<<<12288, 256, 0, stream>>>(q, kbuf, qg + i * HEADS * DH, kg + i * HEADS * DH);
    attn_kernel<<<dim3(24, 16), 256, 0, stream>>>(q, kbuf, vtb, segs, aAq);
    gemm_kernel<<<192, 256, 0, stream>>>(
        aAq, wth + 1769472, wtl + 1769472, nullptr, x, x, nullptr, nullptr,
        DIM, DIM, 12, 0);
    ln_kernel<<<NTOK / 4, 256, 0, stream>>>(x, ln2 + i * DIM, nullptr, aAq);
    gemm_kernel<<<768, 256, 0, stream>>>(
        aAq, wth + 2359296, wtl + 2359296, b1 + i * MLP_, nullptr,
        nullptr, aBq, nullptr, MLP_, DIM, 48, 1);
    gemm_kernel<<<192, 256, 0, stream>>>(
        aBq, wth + 4718592, wtl + 4718592, b2 + i * DIM, x, x, nullptr, nullptr,
        DIM, MLP_, 12, 0);
  }
  ln_kernel<<<NTOK / 4, 256, 0, stream>>>(x, lnf, out, nullptr);
}

// Round 6
// 1328.585 us; speedup vs baseline: 3.1127x; 1.1485x over previous
//
#include <hip/hip_runtime.h>
#include <hip/hip_bf16.h>
#include <math.h>

typedef _Float16 f16;
typedef f16   f16x8 __attribute__((ext_vector_type(8)));
typedef float f32x4 __attribute__((ext_vector_type(4)));
typedef unsigned short ushort_t;

#define DIM   768
#define HEADS 12
#define DH    64
#define MLP_  3072
#define NTOK  2048
#define SEQ   1024
#define WELTS 7077888   // per-layer converted weight elements (Wq+Wkv+Wo+W1+W2)

__device__ __forceinline__ ushort_t h2u(f16 h){ return __builtin_bit_cast(ushort_t, h); }
__device__ __forceinline__ unsigned pk2h(float a, float b){
  return (unsigned)h2u((f16)a) | ((unsigned)h2u((f16)b) << 16);
}
__device__ __forceinline__ void gload16(const void* g, void* l){
  __builtin_amdgcn_global_load_lds(
      (const __attribute__((address_space(1))) void*)g,
      (__attribute__((address_space(3))) void*)l, 16, 0, 0);
}
__device__ __forceinline__ float wred_sum(float v){
  #pragma unroll
  for (int o = 32; o > 0; o >>= 1) v += __shfl_xor(v, o);
  return v;
}

// ---------- weight convert: W[K][N] f32 -> Wt_h/Wt_l [N][K] f16 --------------
__global__ __launch_bounds__(256) void convert_w_kernel(
    const float* __restrict__ Wq, const float* __restrict__ Wkv,
    const float* __restrict__ Wo, const float* __restrict__ W1,
    const float* __restrict__ W2, int layer, int wp_only,
    f16* __restrict__ th, f16* __restrict__ tl)
{
  int bid = blockIdx.x;
  const float* src; int K, N; size_t ooff; int t;
  if (wp_only){ src = Wq; K = 768; N = 768; ooff = 0; t = bid; }
  else if (bid < 288) { src = Wq;  K = 768;  N = 768;  ooff = 0;       t = bid; }
  else if (bid < 864) { src = Wkv; K = 768;  N = 1536; ooff = 589824;  t = bid - 288; }
  else if (bid < 1152){ src = Wo;  K = 768;  N = 768;  ooff = 1769472; t = bid - 864; }
  else if (bid < 2304){ src = W1;  K = 768;  N = 3072; ooff = 2359296; t = bid - 1152; }
  else                { src = W2;  K = 3072; N = 768;  ooff = 4718592; t = bid - 2304; }
  if (!wp_only) src += (size_t)layer * K * N;
  int ntn = N >> 6;
  int tk = t / ntn, tn = t % ntn;
  int k0 = tk * 32, n0 = tn * 64;

  __shared__ ushort_t lh[32][66];
  __shared__ ushort_t ll[32][66];
  int tid = threadIdx.x;
  #pragma unroll
  for (int rr = 0; rr < 2; rr++){
    int k = rr * 16 + (tid >> 4);
    int n = (tid & 15) * 4;
    float4 v = *(const float4*)(src + (size_t)(k0 + k) * N + n0 + n);
    f16 h0 = (f16)v.x, h1 = (f16)v.y, h2 = (f16)v.z, h3 = (f16)v.w;
    lh[k][n+0] = h2u(h0); ll[k][n+0] = h2u((f16)(v.x - (float)h0));
    lh[k][n+1] = h2u(h1); ll[k][n+1] = h2u((f16)(v.y - (float)h1));
    lh[k][n+2] = h2u(h2); ll[k][n+2] = h2u((f16)(v.z - (float)h2));
    lh[k][n+3] = h2u(h3); ll[k][n+3] = h2u((f16)(v.w - (float)h3));
  }
  __syncthreads();
  int n = tid >> 2, kq = tid & 3;
  unsigned ph[4], pl[4];
  #pragma unroll
  for (int j = 0; j < 4; j++){
    ph[j] = (unsigned)lh[kq*8 + 2*j][n] | ((unsigned)lh[kq*8 + 2*j + 1][n] << 16);
    pl[j] = (unsigned)ll[kq*8 + 2*j][n] | ((unsigned)ll[kq*8 + 2*j + 1][n] << 16);
  }
  size_t obase = ooff + (size_t)(n0 + n) * K + k0 + kq * 8;
  *(uint4*)(th + obase) = make_uint4(ph[0], ph[1], ph[2], ph[3]);
  *(uint4*)(tl + obase) = make_uint4(pl[0], pl[1], pl[2], pl[3]);
}

// ---------------- GEMM: C[M,N] = epi(Aq[M,K] @ (Wh+Wl)[N,K]^T) ---------------
// A single fp16, W split fp16 hi/lo, 2 MFMA products. BM=64 BN=64 BK=64,
// 4 waves (2x2 of 32x32). Double-buffered LDS, 1 barrier per K-step
// (prefetch next tile before compute). XOR-swizzled LDS layout.
// mode 0: f32 out (+bias)(+res); mode 1: f16 out of gelu(acc+bias);
// mode 2 (kv): col<768 -> f32 k-buffer; col>=768 -> Vt f16 transposed;
// mode 3: split-K partial f32 to C + z*M*N (no bias/res).
__global__ __launch_bounds__(256) void gemm_kernel(
    const f16* __restrict__ Aq, const f16* __restrict__ Bh, const f16* __restrict__ Bl,
    const float* __restrict__ bias, const float* __restrict__ res,
    float* __restrict__ C, f16* __restrict__ Cq, f16* __restrict__ Vt,
    int N, int K, int nbx, int mode)
{
  __shared__ __align__(16) f16 sA [2][64 * 64];
  __shared__ __align__(16) f16 sBh[2][64 * 64];
  __shared__ __align__(16) f16 sBl[2][64 * 64];
  const int tid = threadIdx.x;
  const int wid = tid >> 6, lane = tid & 63;
  // XCD-chunked swizzle (M-fastest within chunk)
  const int nwg = nbx << 5;
  const int bid = blockIdx.x;
  const int swz = (bid & 7) * (nwg >> 3) + (bid >> 3);
  const int by = swz & 31, bx = swz >> 5;
  const int brow = by << 6, bcol = bx << 6;
  const int m2 = wid & 1, n2 = wid >> 1;
  const int fr = lane & 15, fq = lane >> 4;
  const int Kc = K / (int)gridDim.z;
  const int kbase = (int)blockIdx.z * Kc;
  const int nk = Kc >> 6;

  const f16* pA  = Aq + (size_t)brow * K + kbase;
  const f16* pBh = Bh + (size_t)bcol * K + kbase;
  const f16* pBl = Bl + (size_t)bcol * K + kbase;

  f32x4 acc[2][2] = {};

  auto STAGE = [&](int buf, int ks){
    const int k0 = ks << 6;
    #pragma unroll
    for (int i = 0; i < 2; i++){
      int idx = tid + i * 256;
      int r = idx >> 3, c = idx & 7;
      int gc = c ^ (r & 7);
      gload16(pA  + (size_t)r * K + k0 + gc * 8, &sA [buf][idx * 8]);
      gload16(pBh + (size_t)r * K + k0 + gc * 8, &sBh[buf][idx * 8]);
      gload16(pBl + (size_t)r * K + k0 + gc * 8, &sBl[buf][idx * 8]);
    }
  };

  STAGE(0, 0);
  __syncthreads();
  int cur = 0;
  for (int ks = 0; ks < nk; ks++){
    if (ks + 1 < nk) STAGE(cur ^ 1, ks + 1);
    #pragma unroll
    for (int s = 0; s < 2; s++){
      f16x8 a[2], bh[2], bl[2];
      #pragma unroll
      for (int m = 0; m < 2; m++){
        int r = m2 * 32 + m * 16 + fr;
        int ch = (s * 4 + fq) ^ (r & 7);
        a[m] = *(const f16x8*)(&sA[cur][r * 64 + ch * 8]);
      }
      #pragma unroll
      for (int n = 0; n < 2; n++){
        int r = n2 * 32 + n * 16 + fr;
        int ch = (s * 4 + fq) ^ (r & 7);
        bh[n] = *(const f16x8*)(&sBh[cur][r * 64 + ch * 8]);
        bl[n] = *(const f16x8*)(&sBl[cur][r * 64 + ch * 8]);
      }
      #pragma unroll
      for (int m = 0; m < 2; m++)
        #pragma unroll
        for (int n = 0; n < 2; n++){
          acc[m][n] = __builtin_amdgcn_mfma_f32_16x16x32_f16(a[m], bl[n], acc[m][n], 0, 0, 0);
          acc[m][n] = __builtin_amdgcn_mfma_f32_16x16x32_f16(a[m], bh[n], acc[m][n], 0, 0, 0);
        }
    }
    __syncthreads();
    cur ^= 1;
  }

  // epilogue: D layout col=lane&15, row=(lane>>4)*4+i
  #pragma unroll
  for (int n = 0; n < 2; n++){
    int col = bcol + n2 * 32 + n * 16 + fr;
    float bv = bias ? bias[col] : 0.f;
    #pragma unroll
    for (int m = 0; m < 2; m++){
      int row0 = brow + m2 * 32 + m * 16 + (fq << 2);
      if (mode == 3){
        float* P = C + (size_t)blockIdx.z * ((size_t)NTOK * N);
        #pragma unroll
        for (int i = 0; i < 4; i++)
          P[(size_t)(row0 + i) * N + col] = acc[m][n][i];
      } else if (mode == 2){
        if (col < 768){
          #pragma unroll
          for (int i = 0; i < 4; i++)
            C[(size_t)(row0 + i) * 768 + col] = acc[m][n][i];
        } else {
          int hcol = col - 768, hh = hcol >> 6, dd = hcol & 63;
          int bq = row0 >> 10, tok0 = row0 & 1023;
          ushort4 sv;
          sv.x = h2u((f16)acc[m][n][0]); sv.y = h2u((f16)acc[m][n][1]);
          sv.z = h2u((f16)acc[m][n][2]); sv.w = h2u((f16)acc[m][n][3]);
          *(ushort4*)(Vt + ((size_t)((bq * 12 + hh) * 64 + dd)) * 1024 + tok0) = sv;
        }
      } else if (mode == 1){
        #pragma unroll
        for (int i = 0; i < 4; i++){
          float v = acc[m][n][i] + bv;
          float ge = 0.5f * v * (1.f + erff(v * 0.70710678118654752f));
          Cq[(size_t)(row0 + i) * N + col] = (f16)ge;
        }
      } else {
        #pragma unroll
        for (int i = 0; i < 4; i++){
          float v = acc[m][n][i] + bv;
          size_t o = (size_t)(row0 + i) * N + col;
          if (res) v += res[o];
          C[o] = v;
        }
      }
    }
  }
}

// ---------------- split-K reduce: x += p0 + p1 + bias ------------------------
__global__ __launch_bounds__(256) void reduce_kernel(
    const float* __restrict__ p, const float* __restrict__ b2, float* __restrict__ x)
{
  int idx = blockIdx.x * 256 + threadIdx.x;   // over 2048*768/4 float4
  int cv = idx % 192;
  float4 a = ((const float4*)p)[idx];
  float4 b = ((const float4*)p)[idx + 393216];
  float4 xr = ((const float4*)x)[idx];
  float4 bb = *(const float4*)(b2 + cv * 4);
  xr.x += a.x + b.x + bb.x; xr.y += a.y + b.y + bb.y;
  xr.z += a.z + b.z + bb.z; xr.w += a.w + b.w + bb.w;
  ((float4*)x)[idx] = xr;
}

// ---------------- LayerNorm; out = f32 (yf) or f16 (yq) ----------------------
__global__ __launch_bounds__(256) void ln_kernel(
    const float* __restrict__ x, const float* __restrict__ g,
    float* __restrict__ yf, f16* __restrict__ yq)
{
  int wid = threadIdx.x >> 6, lane = threadIdx.x & 63;
  int row = blockIdx.x * 4 + wid;
  const float* xr = x + (size_t)row * DIM;
  float v[12]; float s = 0.f;
  #pragma unroll
  for (int d = 0; d < 12; d++){ v[d] = xr[d * 64 + lane]; s += v[d]; }
  s = wred_sum(s);
  float mean = s * (1.f / 768.f);
  float q = 0.f;
  #pragma unroll
  for (int d = 0; d < 12; d++){ float t = v[d] - mean; q += t * t; }
  q = wred_sum(q);
  float rstd = rsqrtf(q * (1.f / 768.f) + 1e-5f);
  size_t base = (size_t)row * DIM;
  #pragma unroll
  for (int d = 0; d < 12; d++){
    float y = (v[d] - mean) * rstd * g[d * 64 + lane];
    if (yf) yf[base + d * 64 + lane] = y;
    else    yq[base + d * 64 + lane] = (f16)y;
  }
}

// ------------- fused qk rmsnorm for q and k buffers, in-place ----------------
__global__ __launch_bounds__(256) void rms_kernel(
    float* __restrict__ q, float* __restrict__ kb,
    const float* __restrict__ qg, const float* __restrict__ kg)
{
  int wid = threadIdx.x >> 6, lane = threadIdx.x & 63;
  int id = blockIdx.x * 4 + wid;
  float* p; const float* g;
  int id2 = id < 24576 ? id : id - 24576;
  int tok = id2 / HEADS, h = id2 % HEADS;
  if (id < 24576){ p = q  + (size_t)tok * DIM + h * 64; g = qg + h * 64; }
  else           { p = kb + (size_t)tok * DIM + h * 64; g = kg + h * 64; }
  float v = p[lane];
  float n2 = wred_sum(v * v);
  float nn = fmaxf(sqrtf(n2), 1e-12f);
  p[lane] = v * (8.f / nn) * g[lane];
}

// ---------------- pos-embed add -> f16 ---------------------------------------
__global__ __launch_bounds__(256) void posadd_kernel(
    const float* __restrict__ patches, const int* __restrict__ hi,
    const int* __restrict__ wi, const float* __restrict__ ph,
    const float* __restrict__ pw, f16* __restrict__ oq)
{
  int idx = blockIdx.x * 256 + threadIdx.x;
  int tok = idx / 192, cv = idx % 192;
  float4 p = ((const float4*)patches)[idx];
  float4 a = *(const float4*)(ph + (size_t)hi[tok] * DIM + cv * 4);
  float4 b = *(const float4*)(pw + (size_t)wi[tok] * DIM + cv * 4);
  ushort4 o;
  o.x = h2u((f16)(p.x + a.x + b.x)); o.y = h2u((f16)(p.y + a.y + b.y));
  o.z = h2u((f16)(p.z + a.z + b.z)); o.w = h2u((f16)(p.w + a.w + b.w));
  ((ushort4*)oq)[idx] = o;
}

// ---------------- segment ranges from sorted image_ids -----------------------
__global__ void seg_kernel(const int* __restrict__ ids, int2* __restrict__ segs)
{
  int i = blockIdx.x * 256 + threadIdx.x;
  int b = blockIdx.y;
  const int* row = ids + b * SEQ;
  int v = row[i];
  int lo = 0, hi = SEQ;
  while (lo < hi){ int mid = (lo + hi) >> 1; if (row[mid] <  v) lo = mid + 1; else hi = mid; }
  int s = lo;
  lo = 0; hi = SEQ;
  while (lo < hi){ int mid = (lo + hi) >> 1; if (row[mid] <= v) lo = mid + 1; else hi = mid; }
  segs[b * SEQ + i] = make_int2(s, lo);
}

// --------- MFMA flash attention over segments (all-f16 single product) -------
__global__ __launch_bounds__(256) void attn_kernel(
    const float* __restrict__ qb, const float* __restrict__ kb,
    const f16* __restrict__ vt, const int2* __restrict__ segs,
    f16* __restrict__ oq)
{
  __shared__ ushort_t Kq[32 * 64];
  __shared__ ushort_t Vl[64 * 40];

  const int tid = threadIdx.x;
  const int w = tid >> 6, lane = tid & 63;
  const int q15 = lane & 15, kg = lane >> 4;
  const int bh = blockIdx.x, b = bh / 12, h = bh % 12;
  const int qt = blockIdx.y;
  const int qrow = qt * 64 + w * 16 + q15;
  const size_t qtok = (size_t)b * SEQ + qrow;

  f16x8 qf[2];
  {
    const float* qp = qb + qtok * DIM + h * 64 + kg * 8;
    #pragma unroll
    for (int dh2 = 0; dh2 < 2; dh2++){
      float4 v0 = *(const float4*)(qp + dh2 * 32);
      float4 v1 = *(const float4*)(qp + dh2 * 32 + 4);
      f16x8 f;
      f[0] = (f16)v0.x; f[1] = (f16)v0.y; f[2] = (f16)v0.z; f[3] = (f16)v0.w;
      f[4] = (f16)v1.x; f[5] = (f16)v1.y; f[6] = (f16)v1.z; f[7] = (f16)v1.w;
      qf[dh2] = f;
    }
  }

  const int2 se  = segs[qtok];
  const int2 se0 = segs[(size_t)b * SEQ + qt * 64];
  const int2 se1 = segs[(size_t)b * SEQ + qt * 64 + 63];
  const int klo = se0.x & ~31, khi = se1.y;

  float m = -3.0e38f, l = 0.f;
  f32x4 oacc[4] = {};

  const int krl = tid >> 3, dsl = tid & 7;
  const int vd = tid >> 2, vko = (tid & 3) * 8;

  for (int kt = klo; kt < khi; kt += 32){
    {
      int krow = kt + krl; if (krow > SEQ - 1) krow = SEQ - 1;
      const float* kp = kb + ((size_t)b * SEQ + krow) * DIM + h * 64 + dsl * 8;
      float4 a = *(const float4*)kp, c = *(const float4*)(kp + 4);
      unsigned u0 = pk2h(a.x, a.y), u1 = pk2h(a.z, a.w);
      unsigned u2 = pk2h(c.x, c.y), u3 = pk2h(c.z, c.w);
      unsigned off = ((unsigned)krl << 7) + ((unsigned)dsl << 4);
      off ^= (unsigned)(krl & 7) << 4;
      *(uint4*)((char*)Kq + off) = make_uint4(u0, u1, u2, u3);
      int ksrc = kt + vko; if (ksrc > SEQ - 8) ksrc = SEQ - 8;
      uint4 vv = *(const uint4*)(vt + ((size_t)bh * 64 + vd) * SEQ + ksrc);
      *(uint4*)((char*)Vl + vd * 80 + vko * 2) = vv;
    }
    __syncthreads();

    f32x4 s[2] = {};
    #pragma unroll
    for (int dh2 = 0; dh2 < 2; dh2++){
      #pragma unroll
      for (int khf = 0; khf < 2; khf++){
        int row = khf * 16 + q15;
        unsigned off = ((unsigned)row << 7) + ((unsigned)(dh2 * 4 + kg) << 4);
        off ^= (unsigned)(row & 7) << 4;
        f16x8 kf = *(const f16x8*)((const char*)Kq + off);
        s[khf] = __builtin_amdgcn_mfma_f32_16x16x32_f16(kf, qf[dh2], s[khf], 0, 0, 0);
      }
    }

    float p[8]; float tmax = -3.0e38f;
    #pragma unroll
    for (int khf = 0; khf < 2; khf++)
      #pragma unroll
      for (int i = 0; i < 4; i++){
        int key = kt + khf * 16 + kg * 4 + i;
        bool val = (key >= se.x) && (key < se.y);
        float sv = val ? s[khf][i] : -3.0e38f;
        p[khf * 4 + i] = sv;
        tmax = fmaxf(tmax, sv);
      }
    tmax = fmaxf(tmax, __shfl_xor(tmax, 16));
    tmax = fmaxf(tmax, __shfl_xor(tmax, 32));
    float mnew = fmaxf(m, tmax);
    float sc = __expf(m - mnew);
    float psum = 0.f;
    #pragma unroll
    for (int j = 0; j < 8; j++){
      float pv = (p[j] > -1.0e38f) ? __expf(p[j] - mnew) : 0.f;
      p[j] = pv; psum += pv;
    }
    psum += __shfl_xor(psum, 16);
    psum += __shfl_xor(psum, 32);
    l = l * sc + psum;
    m = mnew;
    #pragma unroll
    for (int dt = 0; dt < 4; dt++) oacc[dt] *= sc;

    unsigned u00 = pk2h(p[0], p[1]), u01 = pk2h(p[2], p[3]);
    unsigned u10 = pk2h(p[4], p[5]), u11 = pk2h(p[6], p[7]);
    int s0l = q15 + ((kg & 1) << 5);
    int s1l = s0l + 16;
    unsigned a0 = __shfl(u00, s0l), b0 = __shfl(u01, s0l);
    unsigned a1 = __shfl(u00, s1l), b1 = __shfl(u01, s1l);
    unsigned c0 = __shfl(u10, s0l), d0 = __shfl(u11, s0l);
    unsigned c1 = __shfl(u10, s1l), d1 = __shfl(u11, s1l);
    bool hih = kg >= 2;
    f16x8 pfrag = __builtin_bit_cast(f16x8,
        make_uint4(hih ? c0 : a0, hih ? d0 : b0, hih ? c1 : a1, hih ? d1 : b1));

    #pragma unroll
    for (int dt = 0; dt < 4; dt++){
      f16x8 vf = *(const f16x8*)((const char*)Vl + (dt * 16 + q15) * 80 + kg * 16);
      oacc[dt] = __builtin_amdgcn_mfma_f32_16x16x32_f16(vf, pfrag, oacc[dt], 0, 0, 0);
    }
    __syncthreads();
  }

  float rl = 1.f / l;
  size_t obase = qtok * DIM + h * 64;
  #pragma unroll
  for (int dt = 0; dt < 4; dt++){
    ushort4 hs;
    hs.x = h2u((f16)(oacc[dt][0] * rl)); hs.y = h2u((f16)(oacc[dt][1] * rl));
    hs.z = h2u((f16)(oacc[dt][2] * rl)); hs.w = h2u((f16)(oacc[dt][3] * rl));
    *(ushort4*)(oq + obase + dt * 16 + kg * 4) = hs;
  }
}

// ---------------- driver -----------------------------------------------------
extern "C" void kernel_launch(void* const* d_in, const int* in_sizes, int n_in,
                              void* d_out, int out_size, void* d_ws, size_t ws_size,
                              hipStream_t stream)
{
  const float* patches   = (const float*)d_in[0];
  const int*   h_idx     = (const int*)d_in[1];
  const int*   w_idx     = (const int*)d_in[2];
  const int*   image_ids = (const int*)d_in[3];
  const float* pos_h = (const float*)d_in[4];
  const float* pos_w = (const float*)d_in[5];
  const float* Wp  = (const float*)d_in[6];
  const float* bp  = (const float*)d_in[7];
  const float* lnp = (const float*)d_in[8];
  const float* ln1 = (const float*)d_in[9];
  const float* qg  = (const float*)d_in[10];
  const float* kg  = (const float*)d_in[11];
  const float* Wq  = (const float*)d_in[12];
  const float* Wkv = (const float*)d_in[13];
  const float* Wo  = (const float*)d_in[14];
  const float* ln2 = (const float*)d_in[15];
  const float* W1  = (const float*)d_in[16];
  const float* b1  = (const float*)d_in[17];
  const float* W2  = (const float*)d_in[18];
  const float* b2  = (const float*)d_in[19];
  const float* lnf = (const float*)d_in[20];
  float* out = (float*)d_out;

  float* ws = (float*)d_ws;
  float* x    = ws;                      // 2048*768 f32
  float* q    = x + NTOK * DIM;          // 2048*768 f32
  float* kbuf = q + NTOK * DIM;          // 2048*768 f32 (k only)
  float* pbuf = kbuf + NTOK * DIM;       // 2*2048*768 f32 split-K partials
  int2* segs = (int2*)(pbuf + 2 * NTOK * DIM);
  f16* aAq = (f16*)(segs + NTOK);        // 2048*768
  f16* aBq = aAq + NTOK * DIM;           // 2048*3072
  f16* wth = aBq + NTOK * MLP_;          // WELTS
  f16* wtl = wth + WELTS;
  f16* vtb = wtl + WELTS;                // 24*64*1024 V^T

  seg_kernel<<<dim3(4, 2), 256, 0, stream>>>(image_ids, segs);
  posadd_kernel<<<1536, 256, 0, stream>>>(patches, h_idx, w_idx, pos_h, pos_w, aAq);
  convert_w_kernel<<<288, 256, 0, stream>>>(Wp, nullptr, nullptr, nullptr, nullptr, 0, 1, wth, wtl);
  gemm_kernel<<<384, 256, 0, stream>>>(
      aAq, wth, wtl, bp, nullptr, q, nullptr, nullptr, DIM, DIM, 12, 0);
  ln_kernel<<<NTOK / 4, 256, 0, stream>>>(q, lnp, x, nullptr);

  for (int i = 0; i < 8; i++){
    convert_w_kernel<<<3456, 256, 0, stream>>>(Wq, Wkv, Wo, W1, W2, i, 0, wth, wtl);
    ln_kernel<<<NTOK / 4, 256, 0, stream>>>(x, ln1 + i * DIM, nullptr, aAq);
    gemm_kernel<<<384, 256, 0, stream>>>(
        aAq, wth + 0, wtl + 0, nullptr, nullptr, q, nullptr, nullptr,
        DIM, DIM, 12, 0);
    gemm_kernel<<<768, 256, 0, stream>>>(
        aAq, wth + 589824, wtl + 589824, nullptr, nullptr, kbuf, nullptr, vtb,
        2 * DIM, DIM, 24, 2);
    rms_kernel<<<12288, 256, 0, stream>>>(q, kbuf, qg + i * HEADS * DH, kg + i * HEADS * DH);
    attn_kernel<<<dim3(24, 16), 256, 0, stream>>>(q, kbuf, vtb, segs, aAq);
    gemm_kernel<<<384, 256, 0, stream>>>(
        aAq, wth + 1769472, wtl + 1769472, nullptr, x, x, nullptr, nullptr,
        DIM, DIM, 12, 0);
    ln_kernel<<<NTOK / 4, 256, 0, stream>>>(x, ln2 + i * DIM, nullptr, aAq);
    gemm_kernel<<<1536, 256, 0, stream>>>(
        aAq, wth + 2359296, wtl + 2359296, b1 + i * MLP_, nullptr,
        nullptr, aBq, nullptr, MLP_, DIM, 48, 1);
    gemm_kernel<<<dim3(384, 1, 2), 256, 0, stream>>>(
        aBq, wth + 4718592, wtl + 4718592, nullptr, nullptr, pbuf, nullptr, nullptr,
        DIM, MLP_, 12, 3);
    reduce_kernel<<<1536, 256, 0, stream>>>(pbuf, b2 + i * DIM, x);
  }
  ln_kernel<<<NTOK / 4, 256, 0, stream>>>(x, lnf, out, nullptr);
}

// Round 7
// 1027.836 us; speedup vs baseline: 4.0235x; 1.2926x over previous
//
#include <hip/hip_runtime.h>
#include <hip/hip_bf16.h>
#include <math.h>

typedef _Float16 f16;
typedef f16   f16x8 __attribute__((ext_vector_type(8)));
typedef float f32x4 __attribute__((ext_vector_type(4)));
typedef unsigned short ushort_t;

#define DIM   768
#define HEADS 12
#define DH    64
#define MLP_  3072
#define NTOK  2048
#define SEQ   1024
#define WELTS 7077888   // per-layer converted weight elements (Wq+Wkv+Wo+W1+W2)

__device__ __forceinline__ ushort_t h2u(f16 h){ return __builtin_bit_cast(ushort_t, h); }
__device__ __forceinline__ unsigned pk2h(float a, float b){
  return (unsigned)h2u((f16)a) | ((unsigned)h2u((f16)b) << 16);
}
__device__ __forceinline__ void gload16(const void* g, void* l){
  __builtin_amdgcn_global_load_lds(
      (const __attribute__((address_space(1))) void*)g,
      (__attribute__((address_space(3))) void*)l, 16, 0, 0);
}
__device__ __forceinline__ float wred_sum(float v){
  #pragma unroll
  for (int o = 32; o > 0; o >>= 1) v += __shfl_xor(v, o);
  return v;
}

// ---------- weight convert: W[K][N] f32 -> Wt [N][K] f16 ---------------------
__global__ __launch_bounds__(256) void convert_w_kernel(
    const float* __restrict__ Wq, const float* __restrict__ Wkv,
    const float* __restrict__ Wo, const float* __restrict__ W1,
    const float* __restrict__ W2, int layer, int wp_only,
    f16* __restrict__ th)
{
  int bid = blockIdx.x;
  const float* src; int K, N; size_t ooff; int t;
  if (wp_only){ src = Wq; K = 768; N = 768; ooff = 0; t = bid; }
  else if (bid < 288) { src = Wq;  K = 768;  N = 768;  ooff = 0;       t = bid; }
  else if (bid < 864) { src = Wkv; K = 768;  N = 1536; ooff = 589824;  t = bid - 288; }
  else if (bid < 1152){ src = Wo;  K = 768;  N = 768;  ooff = 1769472; t = bid - 864; }
  else if (bid < 2304){ src = W1;  K = 768;  N = 3072; ooff = 2359296; t = bid - 1152; }
  else                { src = W2;  K = 3072; N = 768;  ooff = 4718592; t = bid - 2304; }
  if (!wp_only) src += (size_t)layer * K * N;
  int ntn = N >> 6;
  int tk = t / ntn, tn = t % ntn;
  int k0 = tk * 32, n0 = tn * 64;

  __shared__ ushort_t lh[32][66];
  int tid = threadIdx.x;
  #pragma unroll
  for (int rr = 0; rr < 2; rr++){
    int k = rr * 16 + (tid >> 4);
    int n = (tid & 15) * 4;
    float4 v = *(const float4*)(src + (size_t)(k0 + k) * N + n0 + n);
    lh[k][n+0] = h2u((f16)v.x); lh[k][n+1] = h2u((f16)v.y);
    lh[k][n+2] = h2u((f16)v.z); lh[k][n+3] = h2u((f16)v.w);
  }
  __syncthreads();
  int n = tid >> 2, kq = tid & 3;
  unsigned ph[4];
  #pragma unroll
  for (int j = 0; j < 4; j++)
    ph[j] = (unsigned)lh[kq*8 + 2*j][n] | ((unsigned)lh[kq*8 + 2*j + 1][n] << 16);
  size_t obase = ooff + (size_t)(n0 + n) * K + k0 + kq * 8;
  *(uint4*)(th + obase) = make_uint4(ph[0], ph[1], ph[2], ph[3]);
}

// ---------------- GEMM: C[M,N] = epi(Aq[M,K] @ Wt[N,K]^T), single f16 --------
// block = MW*32 x 64, 4 waves (2x2), wave tile = MW*16 x 32. BK=64, dbuf LDS,
// XOR-swizzled layout via pre-swizzled global_load_lds source.
// mode 0: f32 out (+bias)(+res); mode 1: f16 gelu(acc+bias);
// mode 2 (qkv): col<768 -> Qh f16; <1536 -> Kt f16 [bh][tok][64]; else Vt f16 transposed
// mode 3: split-K f32 partial to C + z*NTOK*N.
template<int MW>
__global__ __launch_bounds__(256) void gemm_kernel(
    const f16* __restrict__ Aq, const f16* __restrict__ Bw,
    const float* __restrict__ bias, const float* __restrict__ res,
    float* __restrict__ C, f16* __restrict__ Cq,
    f16* __restrict__ Qh, f16* __restrict__ Kt, f16* __restrict__ Vt,
    int N, int K, int nbx, int mode)
{
  constexpr int BM = MW * 32;
  __shared__ __align__(16) f16 sA[2][BM * 64];
  __shared__ __align__(16) f16 sB[2][64 * 64];
  const int tid = threadIdx.x;
  const int wid = tid >> 6, lane = tid & 63;
  constexpr int nbyl = (MW == 4) ? 4 : 5;
  const int nwg = nbx << nbyl;
  const int bid = blockIdx.x;
  const int swz = (bid & 7) * (nwg >> 3) + (bid >> 3);
  const int by = swz & ((1 << nbyl) - 1), bx = swz >> nbyl;
  const int brow = by * BM, bcol = bx << 6;
  const int m2 = wid & 1, n2 = wid >> 1;
  const int fr = lane & 15, fq = lane >> 4;
  const int Kc = K / (int)gridDim.z;
  const int kbase = (int)blockIdx.z * Kc;
  const int nk = Kc >> 6;

  const f16* pA = Aq + (size_t)brow * K + kbase;
  const f16* pB = Bw + (size_t)bcol * K + kbase;

  f32x4 acc[MW][2] = {};

  auto STAGE = [&](int buf, int ks){
    const int k0 = ks << 6;
    #pragma unroll
    for (int i = 0; i < MW; i++){
      int idx = tid + i * 256;
      int r = idx >> 3, c = idx & 7;
      int gc = c ^ (r & 7);
      gload16(pA + (size_t)r * K + k0 + gc * 8, &sA[buf][idx * 8]);
    }
    #pragma unroll
    for (int i = 0; i < 2; i++){
      int idx = tid + i * 256;
      int r = idx >> 3, c = idx & 7;
      int gc = c ^ (r & 7);
      gload16(pB + (size_t)r * K + k0 + gc * 8, &sB[buf][idx * 8]);
    }
  };

  STAGE(0, 0);
  __syncthreads();
  int cur = 0;
  for (int ks = 0; ks < nk; ks++){
    if (ks + 1 < nk) STAGE(cur ^ 1, ks + 1);
    #pragma unroll
    for (int s = 0; s < 2; s++){
      f16x8 a[MW], b[2];
      #pragma unroll
      for (int m = 0; m < MW; m++){
        int r = m2 * (MW * 16) + m * 16 + fr;
        int ch = (s * 4 + fq) ^ (r & 7);
        a[m] = *(const f16x8*)(&sA[cur][r * 64 + ch * 8]);
      }
      #pragma unroll
      for (int n = 0; n < 2; n++){
        int r = n2 * 32 + n * 16 + fr;
        int ch = (s * 4 + fq) ^ (r & 7);
        b[n] = *(const f16x8*)(&sB[cur][r * 64 + ch * 8]);
      }
      #pragma unroll
      for (int m = 0; m < MW; m++)
        #pragma unroll
        for (int n = 0; n < 2; n++)
          acc[m][n] = __builtin_amdgcn_mfma_f32_16x16x32_f16(a[m], b[n], acc[m][n], 0, 0, 0);
    }
    __syncthreads();
    cur ^= 1;
  }

  // epilogue: D layout col=lane&15, row=(lane>>4)*4+i
  #pragma unroll
  for (int n = 0; n < 2; n++){
    int col = bcol + n2 * 32 + n * 16 + fr;
    float bv = bias ? bias[col] : 0.f;
    #pragma unroll
    for (int m = 0; m < MW; m++){
      int row0 = brow + m2 * (MW * 16) + m * 16 + (fq << 2);
      if (mode == 3){
        float* P = C + (size_t)blockIdx.z * ((size_t)NTOK * N);
        #pragma unroll
        for (int i = 0; i < 4; i++)
          P[(size_t)(row0 + i) * N + col] = acc[m][n][i];
      } else if (mode == 2){
        if (col < 768){
          #pragma unroll
          for (int i = 0; i < 4; i++)
            Qh[(size_t)(row0 + i) * 768 + col] = (f16)acc[m][n][i];
        } else if (col < 1536){
          int hcol = col - 768, hh = hcol >> 6, dd = hcol & 63;
          #pragma unroll
          for (int i = 0; i < 4; i++){
            int row = row0 + i;
            int bq = row >> 10, tok = row & 1023;
            Kt[((size_t)(bq * 12 + hh) * 1024 + tok) * 64 + dd] = (f16)acc[m][n][i];
          }
        } else {
          int hcol = col - 1536, hh = hcol >> 6, dd = hcol & 63;
          int bq = row0 >> 10, tok0 = row0 & 1023;
          ushort4 sv;
          sv.x = h2u((f16)acc[m][n][0]); sv.y = h2u((f16)acc[m][n][1]);
          sv.z = h2u((f16)acc[m][n][2]); sv.w = h2u((f16)acc[m][n][3]);
          *(ushort4*)(Vt + ((size_t)((bq * 12 + hh) * 64 + dd)) * 1024 + tok0) = sv;
        }
      } else if (mode == 1){
        #pragma unroll
        for (int i = 0; i < 4; i++){
          float v = acc[m][n][i] + bv;
          float ge = 0.5f * v * (1.f + erff(v * 0.70710678118654752f));
          Cq[(size_t)(row0 + i) * N + col] = (f16)ge;
        }
      } else {
        #pragma unroll
        for (int i = 0; i < 4; i++){
          float v = acc[m][n][i] + bv;
          size_t o = (size_t)(row0 + i) * N + col;
          if (res) v += res[o];
          C[o] = v;
        }
      }
    }
  }
}

// ------- fused (optional split-K reduce + b2 + residual) + LayerNorm ---------
// if p: x += p0 + p1 + badd (in place), then LN(x)*g -> yq f16 or yf f32.
__global__ __launch_bounds__(256) void lnred_kernel(
    float* __restrict__ x, const float* __restrict__ p, const float* __restrict__ badd,
    const float* __restrict__ g, f16* __restrict__ yq, float* __restrict__ yf)
{
  int wid = threadIdx.x >> 6, lane = threadIdx.x & 63;
  int row = blockIdx.x * 4 + wid;
  float* xr = x + (size_t)row * DIM;
  float v[12]; float s = 0.f;
  if (p){
    const float* p0 = p + (size_t)row * DIM;
    const float* p1 = p0 + (size_t)NTOK * DIM;
    #pragma unroll
    for (int d = 0; d < 12; d++){
      int c = d * 64 + lane;
      float t = xr[c] + p0[c] + p1[c] + badd[c];
      xr[c] = t; v[d] = t; s += t;
    }
  } else {
    #pragma unroll
    for (int d = 0; d < 12; d++){ v[d] = xr[d * 64 + lane]; s += v[d]; }
  }
  s = wred_sum(s);
  float mean = s * (1.f / 768.f);
  float q2 = 0.f;
  #pragma unroll
  for (int d = 0; d < 12; d++){ float t = v[d] - mean; q2 += t * t; }
  q2 = wred_sum(q2);
  float rstd = rsqrtf(q2 * (1.f / 768.f) + 1e-5f);
  size_t base = (size_t)row * DIM;
  #pragma unroll
  for (int d = 0; d < 12; d++){
    float y = (v[d] - mean) * rstd * g[d * 64 + lane];
    if (yq) yq[base + d * 64 + lane] = (f16)y;
    else    yf[base + d * 64 + lane] = y;
  }
}

// ------------- fused qk rmsnorm on f16 q [tok][768] and k [bh][tok][64] ------
__global__ __launch_bounds__(256) void rms_kernel(
    f16* __restrict__ qh, f16* __restrict__ kt,
    const float* __restrict__ qg, const float* __restrict__ kg)
{
  int wid = threadIdx.x >> 6, lane = threadIdx.x & 63;
  int id = blockIdx.x * 4 + wid;            // [0, 49152)
  f16* p; const float* g;
  if (id < 24576){
    int tok = id / HEADS, h = id % HEADS;
    p = qh + (size_t)tok * DIM + h * 64; g = qg + h * 64;
  } else {
    int id2 = id - 24576;
    p = kt + (size_t)id2 * 64; g = kg + ((id2 >> 10) % 12) * 64;
  }
  float v = (float)p[lane];
  float n2 = wred_sum(v * v);
  float nn = fmaxf(sqrtf(n2), 1e-12f);
  p[lane] = (f16)(v * (8.f / nn) * g[lane]);
}

// ---------------- pos-embed add -> f16 ---------------------------------------
__global__ __launch_bounds__(256) void posadd_kernel(
    const float* __restrict__ patches, const int* __restrict__ hi,
    const int* __restrict__ wi, const float* __restrict__ ph,
    const float* __restrict__ pw, f16* __restrict__ oq)
{
  int idx = blockIdx.x * 256 + threadIdx.x;
  int tok = idx / 192, cv = idx % 192;
  float4 p = ((const float4*)patches)[idx];
  float4 a = *(const float4*)(ph + (size_t)hi[tok] * DIM + cv * 4);
  float4 b = *(const float4*)(pw + (size_t)wi[tok] * DIM + cv * 4);
  ushort4 o;
  o.x = h2u((f16)(p.x + a.x + b.x)); o.y = h2u((f16)(p.y + a.y + b.y));
  o.z = h2u((f16)(p.z + a.z + b.z)); o.w = h2u((f16)(p.w + a.w + b.w));
  ((ushort4*)oq)[idx] = o;
}

// ---------------- segment ranges from sorted image_ids -----------------------
__global__ void seg_kernel(const int* __restrict__ ids, int2* __restrict__ segs)
{
  int i = blockIdx.x * 256 + threadIdx.x;
  int b = blockIdx.y;
  const int* row = ids + b * SEQ;
  int v = row[i];
  int lo = 0, hi = SEQ;
  while (lo < hi){ int mid = (lo + hi) >> 1; if (row[mid] <  v) lo = mid + 1; else hi = mid; }
  int s = lo;
  lo = 0; hi = SEQ;
  while (lo < hi){ int mid = (lo + hi) >> 1; if (row[mid] <= v) lo = mid + 1; else hi = mid; }
  segs[b * SEQ + i] = make_int2(s, lo);
}

// --------- MFMA flash attention over segments (all-f16) ----------------------
// K staged via pre-swizzled global_load_lds from f16 Kt (zero VALU convert).
__global__ __launch_bounds__(256) void attn_kernel(
    const f16* __restrict__ qh, const f16* __restrict__ ktp,
    const f16* __restrict__ vt, const int2* __restrict__ segs,
    f16* __restrict__ oq)
{
  __shared__ __align__(16) ushort_t Kq[32 * 64];
  __shared__ __align__(16) ushort_t Vl[64 * 40];

  const int tid = threadIdx.x;
  const int w = tid >> 6, lane = tid & 63;
  const int q15 = lane & 15, kg = lane >> 4;
  const int bh = blockIdx.x, b = bh / 12, h = bh % 12;
  const int qt = blockIdx.y;
  const int qrow = qt * 64 + w * 16 + q15;
  const size_t qtok = (size_t)b * SEQ + qrow;

  // Q fragments (f16), col=lane&15=q, k=d
  const f16* qp = qh + qtok * DIM + h * 64 + kg * 8;
  f16x8 qf[2];
  qf[0] = *(const f16x8*)(qp);
  qf[1] = *(const f16x8*)(qp + 32);

  const int2 se  = segs[qtok];
  const int2 se0 = segs[(size_t)b * SEQ + qt * 64];
  const int2 se1 = segs[(size_t)b * SEQ + qt * 64 + 63];
  const int klo = se0.x & ~31, khi = se1.y;

  float m = -3.0e38f, l = 0.f;
  f32x4 oacc[4] = {};

  const int krl = tid >> 3, kcl = tid & 7;     // K stage: 32 rows x 8 chunks
  const int kgc = kcl ^ (krl & 7);             // pre-swizzled source chunk
  const f16* kbase = ktp + (size_t)bh * 1024 * 64;
  const int vd = tid >> 2, vko = (tid & 3) * 8;

  for (int kt0 = klo; kt0 < khi; kt0 += 32){
    // ---- stage K tile: direct global->LDS, source pre-swizzled ----
    gload16(kbase + (size_t)(kt0 + krl) * 64 + kgc * 8, Kq + tid * 8);
    // ---- stage V^T tile (f16 rows of 32 keys, stride 40) ----
    {
      int ksrc = kt0 + vko;
      uint4 vv = *(const uint4*)(vt + ((size_t)bh * 64 + vd) * SEQ + ksrc);
      *(uint4*)((char*)Vl + vd * 80 + vko * 2) = vv;
    }
    __syncthreads();

    // ---- QK^T: S[key][q] ----
    f32x4 s[2] = {};
    #pragma unroll
    for (int dh2 = 0; dh2 < 2; dh2++){
      #pragma unroll
      for (int khf = 0; khf < 2; khf++){
        int row = khf * 16 + q15;
        unsigned off = ((unsigned)row << 7) + ((unsigned)(dh2 * 4 + kg) << 4);
        off ^= (unsigned)(row & 7) << 4;
        f16x8 kf = *(const f16x8*)((const char*)Kq + off);
        s[khf] = __builtin_amdgcn_mfma_f32_16x16x32_f16(kf, qf[dh2], s[khf], 0, 0, 0);
      }
    }

    // ---- online softmax (q lane-local) ----
    float p[8]; float tmax = -3.0e38f;
    #pragma unroll
    for (int khf = 0; khf < 2; khf++)
      #pragma unroll
      for (int i = 0; i < 4; i++){
        int key = kt0 + khf * 16 + kg * 4 + i;
        bool val = (key >= se.x) && (key < se.y);
        float sv = val ? s[khf][i] : -3.0e38f;
        p[khf * 4 + i] = sv;
        tmax = fmaxf(tmax, sv);
      }
    tmax = fmaxf(tmax, __shfl_xor(tmax, 16));
    tmax = fmaxf(tmax, __shfl_xor(tmax, 32));
    float mnew = fmaxf(m, tmax);
    float sc = __expf(m - mnew);
    float psum = 0.f;
    #pragma unroll
    for (int j = 0; j < 8; j++){
      float pv = (p[j] > -1.0e38f) ? __expf(p[j] - mnew) : 0.f;
      p[j] = pv; psum += pv;
    }
    psum += __shfl_xor(psum, 16);
    psum += __shfl_xor(psum, 32);
    l = l * sc + psum;
    m = mnew;
    #pragma unroll
    for (int dt = 0; dt < 4; dt++) oacc[dt] *= sc;

    // ---- P -> B-frag (pack f16 + 8 shfls) ----
    unsigned u00 = pk2h(p[0], p[1]), u01 = pk2h(p[2], p[3]);
    unsigned u10 = pk2h(p[4], p[5]), u11 = pk2h(p[6], p[7]);
    int s0l = q15 + ((kg & 1) << 5);
    int s1l = s0l + 16;
    unsigned a0 = __shfl(u00, s0l), b0 = __shfl(u01, s0l);
    unsigned a1 = __shfl(u00, s1l), b1 = __shfl(u01, s1l);
    unsigned c0 = __shfl(u10, s0l), d0 = __shfl(u11, s0l);
    unsigned c1 = __shfl(u10, s1l), d1 = __shfl(u11, s1l);
    bool hih = kg >= 2;
    f16x8 pfrag = __builtin_bit_cast(f16x8,
        make_uint4(hih ? c0 : a0, hih ? d0 : b0, hih ? c1 : a1, hih ? d1 : b1));

    // ---- O^T += V^T @ P ----
    #pragma unroll
    for (int dt = 0; dt < 4; dt++){
      f16x8 vf = *(const f16x8*)((const char*)Vl + (dt * 16 + q15) * 80 + kg * 16);
      oacc[dt] = __builtin_amdgcn_mfma_f32_16x16x32_f16(vf, pfrag, oacc[dt], 0, 0, 0);
    }
    __syncthreads();
  }

  // ---- epilogue: O = O^T/l, f16 out ----
  float rl = 1.f / l;
  size_t obase = qtok * DIM + h * 64;
  #pragma unroll
  for (int dt = 0; dt < 4; dt++){
    ushort4 hs;
    hs.x = h2u((f16)(oacc[dt][0] * rl)); hs.y = h2u((f16)(oacc[dt][1] * rl));
    hs.z = h2u((f16)(oacc[dt][2] * rl)); hs.w = h2u((f16)(oacc[dt][3] * rl));
    *(ushort4*)(oq + obase + dt * 16 + kg * 4) = hs;
  }
}

// ---------------- driver -----------------------------------------------------
extern "C" void kernel_launch(void* const* d_in, const int* in_sizes, int n_in,
                              void* d_out, int out_size, void* d_ws, size_t ws_size,
                              hipStream_t stream)
{
  const float* patches   = (const float*)d_in[0];
  const int*   h_idx     = (const int*)d_in[1];
  const int*   w_idx     = (const int*)d_in[2];
  const int*   image_ids = (const int*)d_in[3];
  const float* pos_h = (const float*)d_in[4];
  const float* pos_w = (const float*)d_in[5];
  const float* Wp  = (const float*)d_in[6];
  const float* bp  = (const float*)d_in[7];
  const float* lnp = (const float*)d_in[8];
  const float* ln1 = (const float*)d_in[9];
  const float* qg  = (const float*)d_in[10];
  const float* kg  = (const float*)d_in[11];
  const float* Wq  = (const float*)d_in[12];
  const float* Wkv = (const float*)d_in[13];
  const float* Wo  = (const float*)d_in[14];
  const float* ln2 = (const float*)d_in[15];
  const float* W1  = (const float*)d_in[16];
  const float* b1  = (const float*)d_in[17];
  const float* W2  = (const float*)d_in[18];
  const float* b2  = (const float*)d_in[19];
  const float* lnf = (const float*)d_in[20];
  float* out = (float*)d_out;

  float* ws = (float*)d_ws;
  float* x    = ws;                        // 2048*768 f32
  float* pbuf = x + NTOK * DIM;            // 2*2048*768 f32 (split-K partials / tmp)
  f16* qh  = (f16*)(pbuf + 2 * NTOK * DIM);   // 2048*768
  f16* ktb = qh  + NTOK * DIM;                // 24*1024*64
  f16* vtb = ktb + NTOK * DIM;                // 24*64*1024
  f16* aAq = vtb + NTOK * DIM;                // 2048*768
  f16* aBq = aAq + NTOK * DIM;                // 2048*3072
  f16* wth = aBq + NTOK * MLP_;               // WELTS
  int2* segs = (int2*)(wth + WELTS);

  seg_kernel<<<dim3(4, 2), 256, 0, stream>>>(image_ids, segs);
  posadd_kernel<<<1536, 256, 0, stream>>>(patches, h_idx, w_idx, pos_h, pos_w, aAq);
  convert_w_kernel<<<288, 256, 0, stream>>>(Wp, nullptr, nullptr, nullptr, nullptr, 0, 1, wth);
  gemm_kernel<2><<<384, 256, 0, stream>>>(
      aAq, wth, bp, nullptr, pbuf, nullptr, nullptr, nullptr, nullptr, DIM, DIM, 12, 0);
  lnred_kernel<<<NTOK / 4, 256, 0, stream>>>(pbuf, nullptr, nullptr, lnp, nullptr, x);

  for (int i = 0; i < 8; i++){
    convert_w_kernel<<<3456, 256, 0, stream>>>(Wq, Wkv, Wo, W1, W2, i, 0, wth);
    // fused: x += (prev W2 partials + b2) ; ln1 -> aAq
    lnred_kernel<<<NTOK / 4, 256, 0, stream>>>(
        x, i ? pbuf : nullptr, i ? (b2 + (i - 1) * DIM) : nullptr,
        ln1 + i * DIM, aAq, nullptr);
    // fused q/k/v projection
    gemm_kernel<4><<<576, 256, 0, stream>>>(
        aAq, wth, nullptr, nullptr, nullptr, nullptr, qh, ktb, vtb,
        3 * DIM, DIM, 36, 2);
    rms_kernel<<<12288, 256, 0, stream>>>(qh, ktb, qg + i * DIM, kg + i * DIM);
    attn_kernel<<<dim3(24, 16), 256, 0, stream>>>(qh, ktb, vtb, segs, aAq);
    gemm_kernel<2><<<384, 256, 0, stream>>>(
        aAq, wth + 1769472, nullptr, x, x, nullptr, nullptr, nullptr, nullptr,
        DIM, DIM, 12, 0);
    lnred_kernel<<<NTOK / 4, 256, 0, stream>>>(x, nullptr, nullptr, ln2 + i * DIM, aAq, nullptr);
    gemm_kernel<4><<<768, 256, 0, stream>>>(
        aAq, wth + 2359296, b1 + i * MLP_, nullptr, nullptr, aBq, nullptr, nullptr, nullptr,
        MLP_, DIM, 48, 1);
    gemm_kernel<4><<<dim3(192, 1, 2), 256, 0, stream>>>(
        aBq, wth + 4718592, nullptr, nullptr, pbuf, nullptr, nullptr, nullptr, nullptr,
        DIM, MLP_, 12, 3);
  }
  lnred_kernel<<<NTOK / 4, 256, 0, stream>>>(x, pbuf, b2 + 7 * DIM, lnf, nullptr, out);
}

// Round 8
// 979.225 us; speedup vs baseline: 4.2232x; 1.0496x over previous
//
#include <hip/hip_runtime.h>
#include <hip/hip_bf16.h>
#include <math.h>

typedef _Float16 f16;
typedef f16   f16x8 __attribute__((ext_vector_type(8)));
typedef float f32x4 __attribute__((ext_vector_type(4)));
typedef unsigned short ushort_t;

#define DIM   768
#define HEADS 12
#define DH    64
#define MLP_  3072
#define NTOK  2048
#define SEQ   1024
#define WELTS 7077888   // per-layer converted weight elements (Wq+Wkv+Wo+W1+W2)

__device__ __forceinline__ ushort_t h2u(f16 h){ return __builtin_bit_cast(ushort_t, h); }
__device__ __forceinline__ unsigned pk2h(float a, float b){
  return (unsigned)h2u((f16)a) | ((unsigned)h2u((f16)b) << 16);
}
__device__ __forceinline__ void gload16(const void* g, void* l){
  __builtin_amdgcn_global_load_lds(
      (const __attribute__((address_space(1))) void*)g,
      (__attribute__((address_space(3))) void*)l, 16, 0, 0);
}
__device__ __forceinline__ float wred_sum(float v){
  #pragma unroll
  for (int o = 32; o > 0; o >>= 1) v += __shfl_xor(v, o);
  return v;
}

// ---------- weight convert: W[K][N] f32 -> Wt [N][K] f16 ---------------------
__global__ __launch_bounds__(256) void convert_w_kernel(
    const float* __restrict__ Wq, const float* __restrict__ Wkv,
    const float* __restrict__ Wo, const float* __restrict__ W1,
    const float* __restrict__ W2, int layer, int wp_only,
    f16* __restrict__ th)
{
  int bid = blockIdx.x;
  const float* src; int K, N; size_t ooff; int t;
  if (wp_only){ src = Wq; K = 768; N = 768; ooff = 0; t = bid; }
  else if (bid < 288) { src = Wq;  K = 768;  N = 768;  ooff = 0;       t = bid; }
  else if (bid < 864) { src = Wkv; K = 768;  N = 1536; ooff = 589824;  t = bid - 288; }
  else if (bid < 1152){ src = Wo;  K = 768;  N = 768;  ooff = 1769472; t = bid - 864; }
  else if (bid < 2304){ src = W1;  K = 768;  N = 3072; ooff = 2359296; t = bid - 1152; }
  else                { src = W2;  K = 3072; N = 768;  ooff = 4718592; t = bid - 2304; }
  if (!wp_only) src += (size_t)layer * K * N;
  int ntn = N >> 6;
  int tk = t / ntn, tn = t % ntn;
  int k0 = tk * 32, n0 = tn * 64;

  __shared__ ushort_t lh[32][66];
  int tid = threadIdx.x;
  #pragma unroll
  for (int rr = 0; rr < 2; rr++){
    int k = rr * 16 + (tid >> 4);
    int n = (tid & 15) * 4;
    float4 v = *(const float4*)(src + (size_t)(k0 + k) * N + n0 + n);
    lh[k][n+0] = h2u((f16)v.x); lh[k][n+1] = h2u((f16)v.y);
    lh[k][n+2] = h2u((f16)v.z); lh[k][n+3] = h2u((f16)v.w);
  }
  __syncthreads();
  int n = tid >> 2, kq = tid & 3;
  unsigned ph[4];
  #pragma unroll
  for (int j = 0; j < 4; j++)
    ph[j] = (unsigned)lh[kq*8 + 2*j][n] | ((unsigned)lh[kq*8 + 2*j + 1][n] << 16);
  size_t obase = ooff + (size_t)(n0 + n) * K + k0 + kq * 8;
  *(uint4*)(th + obase) = make_uint4(ph[0], ph[1], ph[2], ph[3]);
}

// ------------- big GEMM: 128x128 block, 4 waves of 64x64, BK=64 --------------
// single-buffer LDS (32KB, 4 blocks/CU), XOR-swizzled via pre-swizzled source.
// mode 1: f16 gelu(acc+bias) -> Cq[N]
// mode 2: qkv epilogue: col<768 -> Qh = norm(q)*8*gq*gk; <1536 -> Kt = norm(k)*8
//         (layout [bh][tok][64]); else Vt transposed [bh][64][1024]
// mode 3: split-K f32 partial -> C + z*NTOK*N
__global__ __launch_bounds__(256) void gemm_big(
    const f16* __restrict__ Aq, const f16* __restrict__ Bw,
    const float* __restrict__ bias,
    float* __restrict__ C, f16* __restrict__ Cq,
    f16* __restrict__ Qh, f16* __restrict__ Kt, f16* __restrict__ Vt,
    const float* __restrict__ qgam, const float* __restrict__ kgam,
    int N, int K, int nbx, int mode)
{
  __shared__ __align__(16) f16 sA[128 * 64];
  __shared__ __align__(16) f16 sB[128 * 64];
  const int tid = threadIdx.x;
  const int wid = tid >> 6, lane = tid & 63;
  const int nwg = nbx << 4;
  const int bid = blockIdx.x;
  const int swz = (bid & 7) * (nwg >> 3) + (bid >> 3);
  const int by = swz & 15, bx = swz >> 4;
  const int brow = by << 7, bcol = bx << 7;
  const int m2 = wid & 1, n2 = wid >> 1;
  const int fr = lane & 15, fq = lane >> 4;
  const int Kc = K / (int)gridDim.z;
  const int kbase = (int)blockIdx.z * Kc;
  const int nk = Kc >> 6;

  const f16* pA = Aq + (size_t)brow * K + kbase;
  const f16* pB = Bw + (size_t)bcol * K + kbase;

  f32x4 acc[4][4] = {};

  for (int ks = 0; ks < nk; ks++){
    const int k0 = ks << 6;
    if (ks) __syncthreads();
    #pragma unroll
    for (int i = 0; i < 4; i++){
      int idx = tid + i * 256;
      int r = idx >> 3, c = idx & 7;
      int gc = c ^ (r & 7);
      gload16(pA + (size_t)r * K + k0 + gc * 8, &sA[idx * 8]);
      gload16(pB + (size_t)r * K + k0 + gc * 8, &sB[idx * 8]);
    }
    __syncthreads();
    #pragma unroll
    for (int s = 0; s < 2; s++){
      f16x8 a[4], b[4];
      #pragma unroll
      for (int m = 0; m < 4; m++){
        int r = m2 * 64 + m * 16 + fr;
        int ch = (s * 4 + fq) ^ (r & 7);
        a[m] = *(const f16x8*)(&sA[r * 64 + ch * 8]);
      }
      #pragma unroll
      for (int n = 0; n < 4; n++){
        int r = n2 * 64 + n * 16 + fr;
        int ch = (s * 4 + fq) ^ (r & 7);
        b[n] = *(const f16x8*)(&sB[r * 64 + ch * 8]);
      }
      #pragma unroll
      for (int m = 0; m < 4; m++)
        #pragma unroll
        for (int n = 0; n < 4; n++)
          acc[m][n] = __builtin_amdgcn_mfma_f32_16x16x32_f16(a[m], b[n], acc[m][n], 0, 0, 0);
    }
  }

  // epilogue: D layout col=lane&15, row=(lane>>4)*4+i
  if (mode == 2){
    const int hbase = bcol + n2 * 64;   // wave-uniform, 64-aligned head block
    if (hbase < 768){
      float gp[4];
      #pragma unroll
      for (int n = 0; n < 4; n++){
        int col = hbase + n * 16 + fr;
        gp[n] = qgam[col] * kgam[col];
      }
      #pragma unroll
      for (int m = 0; m < 4; m++)
        #pragma unroll
        for (int i = 0; i < 4; i++){
          float s = 0.f;
          #pragma unroll
          for (int n = 0; n < 4; n++) s += acc[m][n][i] * acc[m][n][i];
          s += __shfl_xor(s, 1); s += __shfl_xor(s, 2);
          s += __shfl_xor(s, 4); s += __shfl_xor(s, 8);
          float f = 8.f / fmaxf(sqrtf(s), 1e-12f);
          int row = brow + m2 * 64 + m * 16 + (fq << 2) + i;
          #pragma unroll
          for (int n = 0; n < 4; n++)
            Qh[(size_t)row * 768 + hbase + n * 16 + fr] = (f16)(acc[m][n][i] * f * gp[n]);
        }
    } else if (hbase < 1536){
      int hh = (hbase - 768) >> 6;
      #pragma unroll
      for (int m = 0; m < 4; m++)
        #pragma unroll
        for (int i = 0; i < 4; i++){
          float s = 0.f;
          #pragma unroll
          for (int n = 0; n < 4; n++) s += acc[m][n][i] * acc[m][n][i];
          s += __shfl_xor(s, 1); s += __shfl_xor(s, 2);
          s += __shfl_xor(s, 4); s += __shfl_xor(s, 8);
          float f = 8.f / fmaxf(sqrtf(s), 1e-12f);
          int row = brow + m2 * 64 + m * 16 + (fq << 2) + i;
          int bq = row >> 10, tok = row & 1023;
          #pragma unroll
          for (int n = 0; n < 4; n++)
            Kt[((size_t)(bq * 12 + hh) * 1024 + tok) * 64 + n * 16 + fr]
                = (f16)(acc[m][n][i] * f);
        }
    } else {
      int hh = (hbase - 1536) >> 6;
      #pragma unroll
      for (int n = 0; n < 4; n++){
        int dd = n * 16 + fr;
        #pragma unroll
        for (int m = 0; m < 4; m++){
          int row0 = brow + m2 * 64 + m * 16 + (fq << 2);
          int bq = row0 >> 10, tok0 = row0 & 1023;
          ushort4 sv;
          sv.x = h2u((f16)acc[m][n][0]); sv.y = h2u((f16)acc[m][n][1]);
          sv.z = h2u((f16)acc[m][n][2]); sv.w = h2u((f16)acc[m][n][3]);
          *(ushort4*)(Vt + ((size_t)((bq * 12 + hh) * 64 + dd)) * 1024 + tok0) = sv;
        }
      }
    }
  } else if (mode == 1){
    #pragma unroll
    for (int n = 0; n < 4; n++){
      int col = bcol + n2 * 64 + n * 16 + fr;
      float bv = bias[col];
      #pragma unroll
      for (int m = 0; m < 4; m++){
        int row0 = brow + m2 * 64 + m * 16 + (fq << 2);
        #pragma unroll
        for (int i = 0; i < 4; i++){
          float v = acc[m][n][i] + bv;
          float ge = 0.5f * v * (1.f + erff(v * 0.70710678118654752f));
          Cq[(size_t)(row0 + i) * N + col] = (f16)ge;
        }
      }
    }
  } else {  // mode 3
    float* P = C + (size_t)blockIdx.z * ((size_t)NTOK * N);
    #pragma unroll
    for (int n = 0; n < 4; n++){
      int col = bcol + n2 * 64 + n * 16 + fr;
      #pragma unroll
      for (int m = 0; m < 4; m++){
        int row0 = brow + m2 * 64 + m * 16 + (fq << 2);
        #pragma unroll
        for (int i = 0; i < 4; i++)
          P[(size_t)(row0 + i) * N + col] = acc[m][n][i];
      }
    }
  }
}

// ------------- small GEMM (64x64 block, 4 waves of 32x32): f32 out -----------
__global__ __launch_bounds__(256) void gemm_small(
    const f16* __restrict__ Aq, const f16* __restrict__ Bw,
    const float* __restrict__ bias, const float* __restrict__ res,
    float* __restrict__ C, int N, int K, int nbx)
{
  __shared__ __align__(16) f16 sA[2][64 * 64];
  __shared__ __align__(16) f16 sB[2][64 * 64];
  const int tid = threadIdx.x;
  const int wid = tid >> 6, lane = tid & 63;
  const int nwg = nbx << 5;
  const int bid = blockIdx.x;
  const int swz = (bid & 7) * (nwg >> 3) + (bid >> 3);
  const int by = swz & 31, bx = swz >> 5;
  const int brow = by << 6, bcol = bx << 6;
  const int m2 = wid & 1, n2 = wid >> 1;
  const int fr = lane & 15, fq = lane >> 4;
  const int nk = K >> 6;

  const f16* pA = Aq + (size_t)brow * K;
  const f16* pB = Bw + (size_t)bcol * K;

  f32x4 acc[2][2] = {};

  auto STAGE = [&](int buf, int ks){
    const int k0 = ks << 6;
    #pragma unroll
    for (int i = 0; i < 2; i++){
      int idx = tid + i * 256;
      int r = idx >> 3, c = idx & 7;
      int gc = c ^ (r & 7);
      gload16(pA + (size_t)r * K + k0 + gc * 8, &sA[buf][idx * 8]);
      gload16(pB + (size_t)r * K + k0 + gc * 8, &sB[buf][idx * 8]);
    }
  };

  STAGE(0, 0);
  __syncthreads();
  int cur = 0;
  for (int ks = 0; ks < nk; ks++){
    if (ks + 1 < nk) STAGE(cur ^ 1, ks + 1);
    #pragma unroll
    for (int s = 0; s < 2; s++){
      f16x8 a[2], b[2];
      #pragma unroll
      for (int m = 0; m < 2; m++){
        int r = m2 * 32 + m * 16 + fr;
        int ch = (s * 4 + fq) ^ (r & 7);
        a[m] = *(const f16x8*)(&sA[cur][r * 64 + ch * 8]);
      }
      #pragma unroll
      for (int n = 0; n < 2; n++){
        int r = n2 * 32 + n * 16 + fr;
        int ch = (s * 4 + fq) ^ (r & 7);
        b[n] = *(const f16x8*)(&sB[cur][r * 64 + ch * 8]);
      }
      #pragma unroll
      for (int m = 0; m < 2; m++)
        #pragma unroll
        for (int n = 0; n < 2; n++)
          acc[m][n] = __builtin_amdgcn_mfma_f32_16x16x32_f16(a[m], b[n], acc[m][n], 0, 0, 0);
    }
    __syncthreads();
    cur ^= 1;
  }

  #pragma unroll
  for (int n = 0; n < 2; n++){
    int col = bcol + n2 * 32 + n * 16 + fr;
    float bv = bias ? bias[col] : 0.f;
    #pragma unroll
    for (int m = 0; m < 2; m++){
      int row0 = brow + m2 * 32 + m * 16 + (fq << 2);
      #pragma unroll
      for (int i = 0; i < 4; i++){
        float v = acc[m][n][i] + bv;
        size_t o = (size_t)(row0 + i) * N + col;
        if (res) v += res[o];
        C[o] = v;
      }
    }
  }
}

// ------- fused (optional npart-way split-K reduce + badd + residual) + LN ----
__global__ __launch_bounds__(256) void lnred_kernel(
    float* __restrict__ x, const float* __restrict__ p, const float* __restrict__ badd,
    int npart, const float* __restrict__ g, f16* __restrict__ yq, float* __restrict__ yf)
{
  int wid = threadIdx.x >> 6, lane = threadIdx.x & 63;
  int row = blockIdx.x * 4 + wid;
  float* xr = x + (size_t)row * DIM;
  float v[12]; float s = 0.f;
  if (npart){
    #pragma unroll
    for (int d = 0; d < 12; d++){
      int c = d * 64 + lane;
      float t = xr[c] + badd[c];
      for (int j = 0; j < 4; j++)
        t += p[(size_t)j * (NTOK * DIM) + (size_t)row * DIM + c];
      xr[c] = t; v[d] = t; s += t;
    }
  } else {
    #pragma unroll
    for (int d = 0; d < 12; d++){ v[d] = xr[d * 64 + lane]; s += v[d]; }
  }
  s = wred_sum(s);
  float mean = s * (1.f / 768.f);
  float q2 = 0.f;
  #pragma unroll
  for (int d = 0; d < 12; d++){ float t = v[d] - mean; q2 += t * t; }
  q2 = wred_sum(q2);
  float rstd = rsqrtf(q2 * (1.f / 768.f) + 1e-5f);
  size_t base = (size_t)row * DIM;
  #pragma unroll
  for (int d = 0; d < 12; d++){
    float y = (v[d] - mean) * rstd * g[d * 64 + lane];
    if (yq) yq[base + d * 64 + lane] = (f16)y;
    else    yf[base + d * 64 + lane] = y;
  }
}

// ---------------- pos-embed add -> f16 ---------------------------------------
__global__ __launch_bounds__(256) void posadd_kernel(
    const float* __restrict__ patches, const int* __restrict__ hi,
    const int* __restrict__ wi, const float* __restrict__ ph,
    const float* __restrict__ pw, f16* __restrict__ oq)
{
  int idx = blockIdx.x * 256 + threadIdx.x;
  int tok = idx / 192, cv = idx % 192;
  float4 p = ((const float4*)patches)[idx];
  float4 a = *(const float4*)(ph + (size_t)hi[tok] * DIM + cv * 4);
  float4 b = *(const float4*)(pw + (size_t)wi[tok] * DIM + cv * 4);
  ushort4 o;
  o.x = h2u((f16)(p.x + a.x + b.x)); o.y = h2u((f16)(p.y + a.y + b.y));
  o.z = h2u((f16)(p.z + a.z + b.z)); o.w = h2u((f16)(p.w + a.w + b.w));
  ((ushort4*)oq)[idx] = o;
}

// ---------------- segment ranges from sorted image_ids -----------------------
__global__ void seg_kernel(const int* __restrict__ ids, int2* __restrict__ segs)
{
  int i = blockIdx.x * 256 + threadIdx.x;
  int b = blockIdx.y;
  const int* row = ids + b * SEQ;
  int v = row[i];
  int lo = 0, hi = SEQ;
  while (lo < hi){ int mid = (lo + hi) >> 1; if (row[mid] <  v) lo = mid + 1; else hi = mid; }
  int s = lo;
  lo = 0; hi = SEQ;
  while (lo < hi){ int mid = (lo + hi) >> 1; if (row[mid] <= v) lo = mid + 1; else hi = mid; }
  segs[b * SEQ + i] = make_int2(s, lo);
}

// --------- MFMA flash attention over segments (all-f16) ----------------------
__global__ __launch_bounds__(256) void attn_kernel(
    const f16* __restrict__ qh, const f16* __restrict__ ktp,
    const f16* __restrict__ vt, const int2* __restrict__ segs,
    f16* __restrict__ oq)
{
  __shared__ __align__(16) ushort_t Kq[32 * 64];
  __shared__ __align__(16) ushort_t Vl[64 * 40];

  const int tid = threadIdx.x;
  const int w = tid >> 6, lane = tid & 63;
  const int q15 = lane & 15, kg = lane >> 4;
  const int bh = blockIdx.x, b = bh / 12, h = bh % 12;
  const int qt = blockIdx.y;
  const int qrow = qt * 64 + w * 16 + q15;
  const size_t qtok = (size_t)b * SEQ + qrow;

  const f16* qp = qh + qtok * DIM + h * 64 + kg * 8;
  f16x8 qf[2];
  qf[0] = *(const f16x8*)(qp);
  qf[1] = *(const f16x8*)(qp + 32);

  const int2 se  = segs[qtok];
  const int2 se0 = segs[(size_t)b * SEQ + qt * 64];
  const int2 se1 = segs[(size_t)b * SEQ + qt * 64 + 63];
  const int klo = se0.x & ~31, khi = se1.y;

  float m = -3.0e38f, l = 0.f;
  f32x4 oacc[4] = {};

  const int krl = tid >> 3, kcl = tid & 7;
  const int kgc = kcl ^ (krl & 7);
  const f16* kbase = ktp + (size_t)bh * 1024 * 64;
  const int vd = tid >> 2, vko = (tid & 3) * 8;

  for (int kt0 = klo; kt0 < khi; kt0 += 32){
    gload16(kbase + (size_t)(kt0 + krl) * 64 + kgc * 8, Kq + tid * 8);
    {
      int ksrc = kt0 + vko;
      uint4 vv = *(const uint4*)(vt + ((size_t)bh * 64 + vd) * SEQ + ksrc);
      *(uint4*)((char*)Vl + vd * 80 + vko * 2) = vv;
    }
    __syncthreads();

    f32x4 s[2] = {};
    #pragma unroll
    for (int dh2 = 0; dh2 < 2; dh2++){
      #pragma unroll
      for (int khf = 0; khf < 2; khf++){
        int row = khf * 16 + q15;
        unsigned off = ((unsigned)row << 7) + ((unsigned)(dh2 * 4 + kg) << 4);
        off ^= (unsigned)(row & 7) << 4;
        f16x8 kf = *(const f16x8*)((const char*)Kq + off);
        s[khf] = __builtin_amdgcn_mfma_f32_16x16x32_f16(kf, qf[dh2], s[khf], 0, 0, 0);
      }
    }

    float p[8]; float tmax = -3.0e38f;
    #pragma unroll
    for (int khf = 0; khf < 2; khf++)
      #pragma unroll
      for (int i = 0; i < 4; i++){
        int key = kt0 + khf * 16 + kg * 4 + i;
        bool val = (key >= se.x) && (key < se.y);
        float sv = val ? s[khf][i] : -3.0e38f;
        p[khf * 4 + i] = sv;
        tmax = fmaxf(tmax, sv);
      }
    tmax = fmaxf(tmax, __shfl_xor(tmax, 16));
    tmax = fmaxf(tmax, __shfl_xor(tmax, 32));
    float mnew = fmaxf(m, tmax);
    float sc = __expf(m - mnew);
    float psum = 0.f;
    #pragma unroll
    for (int j = 0; j < 8; j++){
      float pv = (p[j] > -1.0e38f) ? __expf(p[j] - mnew) : 0.f;
      p[j] = pv; psum += pv;
    }
    psum += __shfl_xor(psum, 16);
    psum += __shfl_xor(psum, 32);
    l = l * sc + psum;
    m = mnew;
    #pragma unroll
    for (int dt = 0; dt < 4; dt++) oacc[dt] *= sc;

    unsigned u00 = pk2h(p[0], p[1]), u01 = pk2h(p[2], p[3]);
    unsigned u10 = pk2h(p[4], p[5]), u11 = pk2h(p[6], p[7]);
    int s0l = q15 + ((kg & 1) << 5);
    int s1l = s0l + 16;
    unsigned a0 = __shfl(u00, s0l), b0 = __shfl(u01, s0l);
    unsigned a1 = __shfl(u00, s1l), b1 = __shfl(u01, s1l);
    unsigned c0 = __shfl(u10, s0l), d0 = __shfl(u11, s0l);
    unsigned c1 = __shfl(u10, s1l), d1 = __shfl(u11, s1l);
    bool hih = kg >= 2;
    f16x8 pfrag = __builtin_bit_cast(f16x8,
        make_uint4(hih ? c0 : a0, hih ? d0 : b0, hih ? c1 : a1, hih ? d1 : b1));

    #pragma unroll
    for (int dt = 0; dt < 4; dt++){
      f16x8 vf = *(const f16x8*)((const char*)Vl + (dt * 16 + q15) * 80 + kg * 16);
      oacc[dt] = __builtin_amdgcn_mfma_f32_16x16x32_f16(vf, pfrag, oacc[dt], 0, 0, 0);
    }
    __syncthreads();
  }

  float rl = 1.f / l;
  size_t obase = qtok * DIM + h * 64;
  #pragma unroll
  for (int dt = 0; dt < 4; dt++){
    ushort4 hs;
    hs.x = h2u((f16)(oacc[dt][0] * rl)); hs.y = h2u((f16)(oacc[dt][1] * rl));
    hs.z = h2u((f16)(oacc[dt][2] * rl)); hs.w = h2u((f16)(oacc[dt][3] * rl));
    *(ushort4*)(oq + obase + dt * 16 + kg * 4) = hs;
  }
}

// ---------------- driver -----------------------------------------------------
extern "C" void kernel_launch(void* const* d_in, const int* in_sizes, int n_in,
                              void* d_out, int out_size, void* d_ws, size_t ws_size,
                              hipStream_t stream)
{
  const float* patches   = (const float*)d_in[0];
  const int*   h_idx     = (const int*)d_in[1];
  const int*   w_idx     = (const int*)d_in[2];
  const int*   image_ids = (const int*)d_in[3];
  const float* pos_h = (const float*)d_in[4];
  const float* pos_w = (const float*)d_in[5];
  const float* Wp  = (const float*)d_in[6];
  const float* bp  = (const float*)d_in[7];
  const float* lnp = (const float*)d_in[8];
  const float* ln1 = (const float*)d_in[9];
  const float* qg  = (const float*)d_in[10];
  const float* kg  = (const float*)d_in[11];
  const float* Wq  = (const float*)d_in[12];
  const float* Wkv = (const float*)d_in[13];
  const float* Wo  = (const float*)d_in[14];
  const float* ln2 = (const float*)d_in[15];
  const float* W1  = (const float*)d_in[16];
  const float* b1  = (const float*)d_in[17];
  const float* W2  = (const float*)d_in[18];
  const float* b2  = (const float*)d_in[19];
  const float* lnf = (const float*)d_in[20];
  float* out = (float*)d_out;

  float* ws = (float*)d_ws;
  float* x    = ws;                        // 2048*768 f32
  float* pbuf = x + NTOK * DIM;            // 4*2048*768 f32 split-K partials / tmp
  f16* qh  = (f16*)(pbuf + 4 * NTOK * DIM);   // 2048*768
  f16* ktb = qh  + NTOK * DIM;                // 24*1024*64
  f16* vtb = ktb + NTOK * DIM;                // 24*64*1024
  f16* aAq = vtb + NTOK * DIM;                // 2048*768
  f16* aBq = aAq + NTOK * DIM;                // 2048*3072
  f16* wth = aBq + NTOK * MLP_;               // WELTS
  int2* segs = (int2*)(wth + WELTS);

  seg_kernel<<<dim3(4, 2), 256, 0, stream>>>(image_ids, segs);
  posadd_kernel<<<1536, 256, 0, stream>>>(patches, h_idx, w_idx, pos_h, pos_w, aAq);
  convert_w_kernel<<<288, 256, 0, stream>>>(Wp, nullptr, nullptr, nullptr, nullptr, 0, 1, wth);
  gemm_small<<<384, 256, 0, stream>>>(aAq, wth, bp, nullptr, pbuf, DIM, DIM, 12);
  lnred_kernel<<<NTOK / 4, 256, 0, stream>>>(pbuf, nullptr, nullptr, 0, lnp, nullptr, x);

  for (int i = 0; i < 8; i++){
    convert_w_kernel<<<3456, 256, 0, stream>>>(Wq, Wkv, Wo, W1, W2, i, 0, wth);
    // fused: x += (prev-layer W2 partials + b2) ; ln1 -> aAq (f16)
    lnred_kernel<<<NTOK / 4, 256, 0, stream>>>(
        x, pbuf, i ? (b2 + (i - 1) * DIM) : nullptr, i ? 4 : 0,
        ln1 + i * DIM, aAq, nullptr);
    // fused q/k/v projection + qk rmsnorm (gammas folded into q)
    gemm_big<<<288, 256, 0, stream>>>(
        aAq, wth, nullptr, nullptr, nullptr, qh, ktb, vtb,
        qg + i * DIM, kg + i * DIM, 3 * DIM, DIM, 18, 2);
    attn_kernel<<<dim3(24, 16), 256, 0, stream>>>(qh, ktb, vtb, segs, aAq);
    gemm_small<<<384, 256, 0, stream>>>(
        aAq, wth + 1769472, nullptr, x, x, DIM, DIM, 12);
    lnred_kernel<<<NTOK / 4, 256, 0, stream>>>(
        x, nullptr, nullptr, 0, ln2 + i * DIM, aAq, nullptr);
    gemm_big<<<384, 256, 0, stream>>>(
        aAq, wth + 2359296, b1 + i * MLP_, nullptr, aBq, nullptr, nullptr, nullptr,
        nullptr, nullptr, MLP_, DIM, 24, 1);
    gemm_big<<<dim3(96, 1, 4), 256, 0, stream>>>(
        aBq, wth + 4718592, nullptr, pbuf, nullptr, nullptr, nullptr, nullptr,
        nullptr, nullptr, DIM, MLP_, 6, 3);
  }
  lnred_kernel<<<NTOK / 4, 256, 0, stream>>>(x, pbuf, b2 + 7 * DIM, 4, lnf, nullptr, out);
}